// Round 2
// baseline (22607.388 us; speedup 1.0000x reference)
//
#include <hip/hip_runtime.h>
#include <hip/hip_cooperative_groups.h>
#include <math.h>

namespace cg = cooperative_groups;

#define Bq 128
#define Tq 128
#define Vq 5000
#define VP 5120
#define Eq 256
#define Hq 512
#define Lq 128
#define G3H 1536
#define KT 128
#define LROW 136

typedef __attribute__((ext_vector_type(8))) short bf16x8;
typedef __attribute__((ext_vector_type(4))) float f32x4;

__device__ __forceinline__ ushort f2bf(float f) {
    union { float f; unsigned u; } v; v.f = f;
    unsigned r = (v.u + 0x7FFFu + ((v.u >> 16) & 1u)) >> 16;
    return (ushort)r;
}
__device__ __forceinline__ float bf2f(ushort s) {
    union { unsigned u; float f; } v; v.u = ((unsigned)s) << 16;
    return v.f;
}

// ---- MFMA tile accumulate, KT=128: acc += A[MI*32 x Klen] * B[128 x Klen]^T ----
template<int MI>
__device__ __forceinline__ void macT(
    f32x4 (&acc)[MI][4],
    const ushort* __restrict__ A, int lda,
    const ushort* __restrict__ Bm, int ldb,
    int n0, int kbase, int Klen,
    ushort* As, ushort* Bs)
{
    const int NA = 2 * MI;
    const int tid = threadIdx.x;
    const int lane = tid & 63;
    const int w = tid >> 6;
    const int wm = (w >> 1) * (MI * 16);
    const int wn = (w & 1) * 64;
    const int fr = lane & 15;
    const int fk = (lane >> 4) * 8;

    int arow[NA], akc[NA];
    #pragma unroll
    for (int i = 0; i < NA; ++i) {
        int c = tid + i * 256;
        arow[i] = c >> 4; akc[i] = (c & 15) * 8;
    }
    int brow[8], bkc[8];
    #pragma unroll
    for (int i = 0; i < 8; ++i) {
        int c = tid + i * 256;
        brow[i] = c >> 4; bkc[i] = (c & 15) * 8;
    }

    const int nk = Klen / KT;
    bf16x8 ra[NA], rb[8];
    #pragma unroll
    for (int i = 0; i < NA; ++i)
        ra[i] = *(const bf16x8*)(A + (size_t)arow[i] * lda + kbase + akc[i]);
    #pragma unroll
    for (int i = 0; i < 8; ++i)
        rb[i] = *(const bf16x8*)(Bm + (size_t)(n0 + brow[i]) * ldb + kbase + bkc[i]);
    #pragma unroll
    for (int i = 0; i < NA; ++i)
        *(bf16x8*)(As + arow[i] * LROW + akc[i]) = ra[i];
    #pragma unroll
    for (int i = 0; i < 8; ++i)
        *(bf16x8*)(Bs + brow[i] * LROW + bkc[i]) = rb[i];
    __syncthreads();

    for (int kt = 0; kt < nk; ++kt) {
        if (kt + 1 < nk) {
            int kb = kbase + (kt + 1) * KT;
            #pragma unroll
            for (int i = 0; i < NA; ++i)
                ra[i] = *(const bf16x8*)(A + (size_t)arow[i] * lda + kb + akc[i]);
            #pragma unroll
            for (int i = 0; i < 8; ++i)
                rb[i] = *(const bf16x8*)(Bm + (size_t)(n0 + brow[i]) * ldb + kb + bkc[i]);
        }
        #pragma unroll
        for (int ks = 0; ks < 4; ++ks) {
            bf16x8 af[MI], bfv[4];
            const int ko = ks * 32 + fk;
            #pragma unroll
            for (int mi = 0; mi < MI; ++mi)
                af[mi] = *(const bf16x8*)(As + (wm + mi * 16 + fr) * LROW + ko);
            #pragma unroll
            for (int ni = 0; ni < 4; ++ni)
                bfv[ni] = *(const bf16x8*)(Bs + (wn + ni * 16 + fr) * LROW + ko);
            #pragma unroll
            for (int mi = 0; mi < MI; ++mi)
                #pragma unroll
                for (int ni = 0; ni < 4; ++ni)
                    acc[mi][ni] = __builtin_amdgcn_mfma_f32_16x16x32_bf16(
                        af[mi], bfv[ni], acc[mi][ni], 0, 0, 0);
        }
        __syncthreads();
        if (kt + 1 < nk) {
            #pragma unroll
            for (int i = 0; i < NA; ++i)
                *(bf16x8*)(As + arow[i] * LROW + akc[i]) = ra[i];
            #pragma unroll
            for (int i = 0; i < 8; ++i)
                *(bf16x8*)(Bs + brow[i] * LROW + bkc[i]) = rb[i];
            __syncthreads();
        }
    }
}

// ================= device-side phase blocks (shared by mega + fallback) ======

// gi partial: bid in [0,384): nt(12) x mq(4) x z(8); z in low bits -> per-XCD
// WcombT working set = 1536x640x2B ~= 1.97 MB < 4 MB per-XCD L2.
__device__ __forceinline__ void gi_block(
    int bid, const ushort* __restrict__ yE, const ushort* __restrict__ WcombT,
    ushort* __restrict__ gip, ushort* As, ushort* Bs)
{
    const int tid = threadIdx.x;
    const int lane = tid & 63, w = tid >> 6;
    const int fr = lane & 15, hi = lane >> 4;
    const int nt = bid >> 5, rem = bid & 31;
    const int mq = rem >> 3, z = rem & 7;
    const int wm = (w >> 1) * 16, wn = (w & 1) * 64;
    const int n0 = nt * 128;
    f32x4 acc[1][4];
    #pragma unroll
    for (int ni = 0; ni < 4; ++ni) acc[0][ni] = (f32x4){0.f,0.f,0.f,0.f};
    macT<1>(acc, yE + (size_t)mq * 32 * VP, VP, WcombT, VP,
            n0, z * 640, 640, As, Bs);
    ushort* C = gip + (size_t)z * (Bq * G3H) + (size_t)mq * 32 * G3H;
    #pragma unroll
    for (int ni = 0; ni < 4; ++ni) {
        int n = n0 + wn + ni * 16 + fr;
        #pragma unroll
        for (int r = 0; r < 4; ++r) {
            int m = wm + hi * 4 + r;
            C[(size_t)m * G3H + n] = f2bf(acc[0][ni][r]);
        }
    }
}

// gh partial: j in [0,48): nt(12) x mh(2) x kc(2), MI=2
__device__ __forceinline__ void gh_block(
    int j, const ushort* __restrict__ hBsrc, const ushort* __restrict__ WhhB,
    ushort* __restrict__ ghp, ushort* As, ushort* Bs)
{
    const int tid = threadIdx.x;
    const int lane = tid & 63, w = tid >> 6;
    const int fr = lane & 15, hi = lane >> 4;
    const int nt = j >> 2, rem = j & 3;
    const int mh = rem >> 1, kc = rem & 1;
    const int n0 = nt * 128;
    const int wm = (w >> 1) * 32, wn = (w & 1) * 64;
    f32x4 acc[2][4];
    #pragma unroll
    for (int mi = 0; mi < 2; ++mi)
        #pragma unroll
        for (int ni = 0; ni < 4; ++ni) acc[mi][ni] = (f32x4){0.f,0.f,0.f,0.f};
    macT<2>(acc, hBsrc + (size_t)mh * 64 * Hq, Hq, WhhB, Hq,
            n0, kc * 256, 256, As, Bs);
    ushort* C = ghp + (size_t)kc * (Bq * G3H);
    #pragma unroll
    for (int mi = 0; mi < 2; ++mi)
        #pragma unroll
        for (int ni = 0; ni < 4; ++ni) {
            int n = n0 + wn + ni * 16 + fr;
            #pragma unroll
            for (int r = 0; r < 4; ++r) {
                int m = mh * 64 + wm + mi * 16 + hi * 4 + r;
                C[(size_t)m * G3H + n] = f2bf(acc[mi][ni][r]);
            }
        }
}

// gates: bid in [0,256)
__device__ __forceinline__ void gates_block(
    int bid, const ushort* __restrict__ gip, const ushort* __restrict__ ghp,
    const float* __restrict__ b_ih, const float* __restrict__ b_hh,
    const float* __restrict__ h_old, const float* __restrict__ esumAll,
    float* __restrict__ h_new, ushort* __restrict__ hB_new, int t, float* sred)
{
    const int tid = threadIdx.x;
    const int e = bid * 256 + tid;   // 65536 total
    const int b = e >> 9, i = e & 511;
    if (t > 0) {
        if (tid < 40) sred[tid] = esumAll[(size_t)(t - 1) * 5120 + tid * 128 + b];
        __syncthreads();
        if (tid == 0) {
            float S = 0.f;
            #pragma unroll
            for (int nt = 0; nt < 40; ++nt) S += sred[nt];
            sred[63] = 1.0f / S;
        }
        __syncthreads();
    } else {
        if (tid == 0) sred[63] = 1.0f;
        __syncthreads();
    }
    const float invS = sred[63];
    __syncthreads();

    const size_t o = (size_t)b * G3H + i;
    float xr = 0.f, xz = 0.f, xn = 0.f;
    #pragma unroll
    for (int z = 0; z < 8; ++z) {
        const ushort* gp = gip + (size_t)z * (Bq * G3H) + o;
        xr += bf2f(gp[0]); xz += bf2f(gp[Hq]); xn += bf2f(gp[2 * Hq]);
    }
    xr = xr * invS + b_ih[i];
    xz = xz * invS + b_ih[Hq + i];
    xn = xn * invS + b_ih[2 * Hq + i];
    const ushort* h0p = ghp + o;
    const ushort* h1p = ghp + (size_t)(Bq * G3H) + o;
    float hr = b_hh[i] + bf2f(h0p[0]) + bf2f(h1p[0]);
    float hz = b_hh[Hq + i] + bf2f(h0p[Hq]) + bf2f(h1p[Hq]);
    float hn = b_hh[2 * Hq + i] + bf2f(h0p[2 * Hq]) + bf2f(h1p[2 * Hq]);
    float r = 1.f / (1.f + expf(-(xr + hr)));
    float zz = 1.f / (1.f + expf(-(xz + hz)));
    float nn = tanhf(xn + r * hn);
    float hv = (1.f - zz) * nn + zz * h_old[e];
    h_new[e] = hv;
    hB_new[e] = f2bf(hv);
}

// logits: bid in [0,160): nt = bid%40 (blocks sharing WoutB slice differ by 40
// -> same XCD under %8 round-robin), mbase = (bid/40)*32
__device__ __forceinline__ void logits_block(
    int bid, const ushort* __restrict__ hB, const ushort* __restrict__ WoutB,
    const float* __restrict__ b_out, const float* __restrict__ gum,
    const float* __restrict__ temp, float* __restrict__ out,
    ushort* __restrict__ yE, float* __restrict__ esumAll, int t,
    ushort* As, ushort* Bs)
{
    const int tid = threadIdx.x;
    const int lane = tid & 63, w = tid >> 6;
    const int fr = lane & 15, hi = lane >> 4;
    const int nt = bid % 40;
    const int mbase = (bid / 40) * 32;
    const int n0 = nt * 128;
    const int wm = (w >> 1) * 16, wn = (w & 1) * 64;
    const float inv_tau = 1.0f / temp[0];
    f32x4 acc[1][4];
    #pragma unroll
    for (int ni = 0; ni < 4; ++ni) acc[0][ni] = (f32x4){0.f,0.f,0.f,0.f};
    macT<1>(acc, hB + (size_t)mbase * Hq, Hq, WoutB, Hq, n0, 0, Hq, As, Bs);

    float psum[4] = {0.f, 0.f, 0.f, 0.f};
    #pragma unroll
    for (int ni = 0; ni < 4; ++ni) {
        int v = n0 + wn + ni * 16 + fr;
        bool valid = v < Vq;
        float bo = valid ? b_out[v] : 0.f;
        #pragma unroll
        for (int r = 0; r < 4; ++r) {
            int m = mbase + wm + hi * 4 + r;
            float ev = 0.f;
            if (valid) {
                float g = gum[(size_t)m * Vq + v];
                ev = expf((acc[0][ni][r] + bo + g) * inv_tau);
                out[(size_t)m * Tq * Vq + (size_t)t * Vq + v] = ev;
            }
            yE[(size_t)m * VP + v] = f2bf(ev);
            psum[r] += ev;
        }
    }
    float* redbuf = (float*)As;   // safe: macT ended with __syncthreads
    #pragma unroll
    for (int r = 0; r < 4; ++r) {
        float s = psum[r];
        s += __shfl_xor(s, 1); s += __shfl_xor(s, 2);
        s += __shfl_xor(s, 4); s += __shfl_xor(s, 8);
        if (fr == 0)
            redbuf[((wm + hi * 4 + r) << 1) | (wn >> 6)] = s;
    }
    __syncthreads();
    if (tid < 32)
        esumAll[(size_t)t * 5120 + n0 + mbase + tid]
            = redbuf[tid * 2] + redbuf[tid * 2 + 1];
}

// normalize two output rows of step tprev
__device__ __forceinline__ void norm2(
    int bpair, int tprev, float* __restrict__ out,
    const float* __restrict__ esumAll)
{
    const int tid = threadIdx.x;
    #pragma unroll
    for (int j = 0; j < 2; ++j) {
        int b = bpair * 2 + j;
        float S = 0.f;
        #pragma unroll 8
        for (int nt = 0; nt < 40; ++nt)
            S += esumAll[(size_t)tprev * 5120 + nt * 128 + b];
        float inv = 1.0f / S;
        float* orow = out + ((size_t)b * Tq + tprev) * Vq;
        #pragma unroll
        for (int i = 0; i < 20; ++i) {
            int v = tid + i * 256;
            if (v < Vq) orow[v] *= inv;
        }
    }
}

// ================= persistent cooperative mega-kernel ========================
__global__ __launch_bounds__(256, 2) void k_mega(
    ushort* yE, const ushort* WcombT, ushort* hB, float* h,
    const ushort* WhhB, ushort* gip, ushort* ghp,
    const ushort* WoutB, const float* b_out, const float* gumbel,
    const float* temp, float* out, float* esumAll,
    const float* b_ih, const float* b_hh)
{
    cg::grid_group grid = cg::this_grid();
    __shared__ __align__(16) ushort As[64 * LROW];
    __shared__ __align__(16) ushort Bs[128 * LROW];
    const int bid = blockIdx.x;

    // pre-phase: gh(0) from hB ping-pong slot 0 (written by k_wh0)
    if (bid < 48)
        gh_block(bid, hB, WhhB, ghp, As, Bs);
    grid.sync();

    for (int t = 0; t < Tq; ++t) {
        float* h_old = h + (size_t)(t & 1) * 65536;
        float* h_new = h + (size_t)((t + 1) & 1) * 65536;
        ushort* hB_new = hB + (size_t)((t + 1) & 1) * 65536;

        // P1: gi partials (all 384 blocks)
        gi_block(bid, yE, WcombT, gip, As, Bs);
        grid.sync();

        // P2: gates + norm(t-1)
        if (bid < 256)
            gates_block(bid, gip, ghp, b_ih, b_hh, h_old, esumAll,
                        h_new, hB_new, t, (float*)As);
        else if (bid < 320) {
            if (t > 0) norm2(bid - 256, t - 1, out, esumAll);
        }
        grid.sync();

        // P3: logits(t) + gh(t+1)
        if (bid < 160)
            logits_block(bid, hB_new, WoutB, b_out,
                         gumbel + (size_t)t * Bq * Vq, temp,
                         out, yE, esumAll, t, As, Bs);
        else if (bid < 208) {
            if (t + 1 < Tq)
                gh_block(bid - 160, hB_new, WhhB, ghp, As, Bs);
        }
        grid.sync();
    }

    // tail: normalize out[:, T-1, :]
    if (bid < 64)
        norm2(bid, Tq - 1, out, esumAll);
}

// ================= prep / wh0 (unchanged) ====================================
__global__ __launch_bounds__(256) void k_prep(
    const float* __restrict__ W_ih, const float* __restrict__ W_hh,
    const float* __restrict__ W_out, const float* __restrict__ noise,
    const float* __restrict__ W_init, const float* __restrict__ emb,
    ushort* __restrict__ WihB, ushort* __restrict__ WhhB, ushort* __restrict__ WoutB,
    ushort* __restrict__ noiseB, ushort* __restrict__ WinitB,
    ushort* __restrict__ embB, ushort* __restrict__ yE)
{
    const int tg = blockIdx.x * 256 + threadIdx.x;
    const int NTH = gridDim.x * 256;
    for (int i = tg; i < G3H * Eq / 4; i += NTH) {
        float4 f = *(const float4*)(W_ih + (size_t)i * 4);
        *(ushort4*)(WihB + (size_t)i * 4) =
            make_ushort4(f2bf(f.x), f2bf(f.y), f2bf(f.z), f2bf(f.w));
    }
    for (int i = tg; i < G3H * Hq / 4; i += NTH) {
        float4 f = *(const float4*)(W_hh + (size_t)i * 4);
        *(ushort4*)(WhhB + (size_t)i * 4) =
            make_ushort4(f2bf(f.x), f2bf(f.y), f2bf(f.z), f2bf(f.w));
    }
    for (int i = tg; i < VP * (Hq / 4); i += NTH) {
        int v = i >> 7, h4 = (i & 127) << 2;
        ushort4 o = make_ushort4(0, 0, 0, 0);
        if (v < Vq) {
            float4 f = *(const float4*)(W_out + (size_t)v * Hq + h4);
            o = make_ushort4(f2bf(f.x), f2bf(f.y), f2bf(f.z), f2bf(f.w));
        }
        *(ushort4*)(WoutB + (size_t)v * Hq + h4) = o;
    }
    for (int i = tg; i < VP * (Eq / 4); i += NTH) {
        int v = i >> 6, e4 = (i & 63) << 2;
        ushort4 o = make_ushort4(0, 0, 0, 0);
        if (v < Vq) {
            float4 f = *(const float4*)(emb + (size_t)v * Eq + e4);
            o = make_ushort4(f2bf(f.x), f2bf(f.y), f2bf(f.z), f2bf(f.w));
        }
        *(ushort4*)(embB + (size_t)v * Eq + e4) = o;
    }
    for (int i = tg; i < Bq * Lq / 4; i += NTH) {
        float4 f = *(const float4*)(noise + (size_t)i * 4);
        *(ushort4*)(noiseB + (size_t)i * 4) =
            make_ushort4(f2bf(f.x), f2bf(f.y), f2bf(f.z), f2bf(f.w));
    }
    for (int i = tg; i < Hq * Lq / 4; i += NTH) {
        float4 f = *(const float4*)(W_init + (size_t)i * 4);
        *(ushort4*)(WinitB + (size_t)i * 4) =
            make_ushort4(f2bf(f.x), f2bf(f.y), f2bf(f.z), f2bf(f.w));
    }
    for (int i = tg; i < Bq * (VP / 4); i += NTH) {
        int v4 = i % (VP / 4);
        ushort4 o = (v4 == 0) ? make_ushort4(0x3F80, 0, 0, 0)
                              : make_ushort4(0, 0, 0, 0);
        *(ushort4*)(yE + (size_t)i * 4) = o;
    }
}

__global__ __launch_bounds__(256) void k_wh0(
    const ushort* __restrict__ WihB, const ushort* __restrict__ embB,
    const ushort* __restrict__ noiseB, const ushort* __restrict__ WinitB,
    const float* __restrict__ b_init,
    ushort* __restrict__ WcombT, float* __restrict__ h0, ushort* __restrict__ hB0)
{
    __shared__ __align__(16) ushort As[128 * LROW];
    __shared__ __align__(16) ushort Bs[128 * LROW];
    const int bid = blockIdx.x;
    const int lane = threadIdx.x & 63;
    const int w = threadIdx.x >> 6;
    const int wm = (w >> 1) * 64, wn = (w & 1) * 64;
    const int fr = lane & 15, hi = lane >> 4;
    f32x4 acc[4][4];
    #pragma unroll
    for (int mi = 0; mi < 4; ++mi)
        #pragma unroll
        for (int ni = 0; ni < 4; ++ni) acc[mi][ni] = (f32x4){0.f,0.f,0.f,0.f};
    if (bid < 480) {
        int mt = bid / 40, nt = bid % 40;
        macT<4>(acc, WihB + (size_t)mt * 128 * Eq, Eq, embB, Eq,
                nt * 128, 0, Eq, As, Bs);
        #pragma unroll
        for (int mi = 0; mi < 4; ++mi)
            #pragma unroll
            for (int ni = 0; ni < 4; ++ni) {
                int n = nt * 128 + wn + ni * 16 + fr;
                #pragma unroll
                for (int r = 0; r < 4; ++r) {
                    int m = mt * 128 + wm + mi * 16 + hi * 4 + r;
                    WcombT[(size_t)m * VP + n] = f2bf(acc[mi][ni][r]);
                }
            }
    } else {
        int n0 = (bid - 480) * 128;
        macT<4>(acc, noiseB, Lq, WinitB, Lq, n0, 0, Lq, As, Bs);
        #pragma unroll
        for (int mi = 0; mi < 4; ++mi)
            #pragma unroll
            for (int ni = 0; ni < 4; ++ni) {
                int n = n0 + wn + ni * 16 + fr;
                float bv = b_init[n];
                #pragma unroll
                for (int r = 0; r < 4; ++r) {
                    int m = wm + mi * 16 + hi * 4 + r;
                    float v = acc[mi][ni][r] + bv;
                    h0[(size_t)m * Hq + n] = v;
                    hB0[(size_t)m * Hq + n] = f2bf(v);
                }
            }
    }
}

// ================= fallback per-step kernels (non-cooperative path) ==========
__global__ __launch_bounds__(256) void k_gi_f(
    const ushort* __restrict__ yE, const ushort* __restrict__ WcombT,
    const ushort* __restrict__ hB_old, const ushort* __restrict__ WhhB,
    ushort* __restrict__ gip, ushort* __restrict__ ghp)
{
    __shared__ __align__(16) ushort As[64 * LROW];
    __shared__ __align__(16) ushort Bs[128 * LROW];
    if (blockIdx.x < 384)
        gi_block(blockIdx.x, yE, WcombT, gip, As, Bs);
    else
        gh_block(blockIdx.x - 384, hB_old, WhhB, ghp, As, Bs);
}

__global__ __launch_bounds__(256) void k_gates_f(
    const ushort* __restrict__ gip, const ushort* __restrict__ ghp,
    const float* __restrict__ b_ih, const float* __restrict__ b_hh,
    const float* __restrict__ h_old, const float* __restrict__ esumAll,
    float* __restrict__ h_new, ushort* __restrict__ hB_new, int t)
{
    __shared__ float sred[64];
    gates_block(blockIdx.x, gip, ghp, b_ih, b_hh, h_old, esumAll,
                h_new, hB_new, t, sred);
}

__global__ __launch_bounds__(256) void k_logits_f(
    const ushort* __restrict__ hB, const ushort* __restrict__ WoutB,
    const ushort* __restrict__ WhhB,
    const float* __restrict__ b_out, const float* __restrict__ gum,
    const float* __restrict__ temp,
    float* __restrict__ out, ushort* __restrict__ yE,
    float* __restrict__ esumAll, ushort* __restrict__ ghp, int t)
{
    __shared__ __align__(16) ushort As[64 * LROW];
    __shared__ __align__(16) ushort Bs[128 * LROW];
    const int bid = blockIdx.x;
    if (bid < 160)
        logits_block(bid, hB, WoutB, b_out, gum, temp, out, yE, esumAll, t,
                     As, Bs);
    else if (bid < 208) {
        if (t + 1 < Tq)
            gh_block(bid - 160, hB, WhhB, ghp, As, Bs);
    } else if (t > 0)
        norm2(bid - 208, t - 1, out, esumAll);
}

__global__ __launch_bounds__(256) void k_tail_f(
    float* __restrict__ out, const float* __restrict__ esumAll)
{
    norm2(blockIdx.x, Tq - 1, out, esumAll);
}

// ================= host ======================================================
extern "C" void kernel_launch(void* const* d_in, const int* in_sizes, int n_in,
                              void* d_out, int out_size, void* d_ws, size_t ws_size,
                              hipStream_t stream)
{
    const float* noise   = (const float*)d_in[0];
    const float* gumbel  = (const float*)d_in[1];
    const float* temp    = (const float*)d_in[2];
    const float* W_init  = (const float*)d_in[3];
    const float* b_init  = (const float*)d_in[4];
    const float* emb     = (const float*)d_in[5];
    const float* W_ih    = (const float*)d_in[6];
    const float* W_hh    = (const float*)d_in[7];
    const float* b_ih    = (const float*)d_in[8];
    const float* b_hh    = (const float*)d_in[9];
    const float* W_out   = (const float*)d_in[10];
    const float* b_out   = (const float*)d_in[11];
    float* out = (float*)d_out;

    float* fbase   = (float*)d_ws;
    float* h       = fbase;                       // 2 * 65536
    float* esumAll = h + 2 * 65536;               // 128 * 5120 = 655360
    ushort* ub     = (ushort*)(esumAll + 655360);
    ushort* gip    = ub;                          // 8 * 196608 = 1572864
    ushort* ghp    = gip + 1572864;               // 2 * 196608 = 393216
    ushort* embB   = ghp + 393216;                // 1310720
    ushort* WihB   = embB + 1310720;              // 393216
    ushort* WhhB   = WihB + 393216;               // 786432
    ushort* WoutB  = WhhB + 786432;               // 2621440
    ushort* WcombT = WoutB + 2621440;             // 7864320
    ushort* noiseB = WcombT + 7864320;            // 16384
    ushort* WinitB = noiseB + 16384;              // 65536
    ushort* hB     = WinitB + 65536;              // 2 * 65536
    ushort* yE     = hB + 2 * 65536;              // 655360

    k_prep<<<dim3(512), dim3(256), 0, stream>>>(
        W_ih, W_hh, W_out, noise, W_init, emb,
        WihB, WhhB, WoutB, noiseB, WinitB, embB, yE);
    k_wh0<<<dim3(484), dim3(256), 0, stream>>>(
        WihB, embB, noiseB, WinitB, b_init, WcombT, h, hB);

    // cooperative persistent path: one kernel for the whole T loop
    {
        void* margs[15];
        margs[0]  = (void*)&yE;      margs[1]  = (void*)&WcombT;
        margs[2]  = (void*)&hB;      margs[3]  = (void*)&h;
        margs[4]  = (void*)&WhhB;    margs[5]  = (void*)&gip;
        margs[6]  = (void*)&ghp;     margs[7]  = (void*)&WoutB;
        margs[8]  = (void*)&b_out;   margs[9]  = (void*)&gumbel;
        margs[10] = (void*)&temp;    margs[11] = (void*)&out;
        margs[12] = (void*)&esumAll; margs[13] = (void*)&b_ih;
        margs[14] = (void*)&b_hh;
        hipError_t e = hipLaunchCooperativeKernel(
            (const void*)k_mega, dim3(384), dim3(256), margs, 0, stream);
        if (e == hipSuccess) return;
        (void)hipGetLastError();   // clear error state, fall back
    }

    // fallback: per-step launches (previous verified structure)
    for (int t = 0; t < Tq; ++t) {
        float* h_old = h + (size_t)(t & 1) * 65536;
        float* h_new = h + (size_t)((t + 1) & 1) * 65536;
        ushort* hB_old = hB + (size_t)(t & 1) * 65536;
        ushort* hB_new = hB + (size_t)((t + 1) & 1) * 65536;

        k_gi_f<<<dim3(t == 0 ? 432 : 384), dim3(256), 0, stream>>>(
            yE, WcombT, hB_old, WhhB, gip, ghp);
        k_gates_f<<<dim3(256), dim3(256), 0, stream>>>(
            gip, ghp, b_ih, b_hh, h_old, esumAll, h_new, hB_new, t);
        k_logits_f<<<dim3(272), dim3(256), 0, stream>>>(
            hB_new, WoutB, WhhB, b_out, gumbel + (size_t)t * Bq * Vq, temp,
            out, yE, esumAll, ghp, t);
    }
    k_tail_f<<<dim3(64), dim3(256), 0, stream>>>(out, esumAll);
}

// Round 3
// 11474.867 us; speedup vs baseline: 1.9702x; 1.9702x over previous
//
#include <hip/hip_runtime.h>
#include <math.h>

#define Bq 128
#define Tq 128
#define Vq 5000
#define VP 5120
#define Eq 256
#define Hq 512
#define Lq 128
#define G3H 1536
#define KT 128
#define LROW 136

typedef __attribute__((ext_vector_type(8))) short bf16x8;
typedef __attribute__((ext_vector_type(4))) float f32x4;

__device__ __forceinline__ ushort f2bf(float f) {
    union { float f; unsigned u; } v; v.f = f;
    unsigned r = (v.u + 0x7FFFu + ((v.u >> 16) & 1u)) >> 16;
    return (ushort)r;
}
__device__ __forceinline__ float bf2f(ushort s) {
    union { unsigned u; float f; } v; v.u = ((unsigned)s) << 16;
    return v.f;
}

// ---------------- custom grid barrier (two-level, device-scope) -------------
// bar layout (uints): [32*g] g=0..7 group counters, [32*8] global counter,
// [32*9] generation word. 384 blocks = 8 groups x 48.
__device__ __forceinline__ void spin_gen(unsigned* gen, unsigned target) {
    while (__hip_atomic_load(gen, __ATOMIC_RELAXED, __HIP_MEMORY_SCOPE_AGENT) < target)
        __builtin_amdgcn_s_sleep(1);
    (void)__hip_atomic_load(gen, __ATOMIC_ACQUIRE, __HIP_MEMORY_SCOPE_AGENT);
}

__device__ __forceinline__ void gridbar(unsigned* bar, unsigned target) {
    __syncthreads();
    if (threadIdx.x == 0) {
        unsigned* gcnt = bar + 32 * (blockIdx.x / 48);
        unsigned* ccnt = bar + 32 * 8;
        unsigned* gen  = bar + 32 * 9;
        unsigned p = __hip_atomic_fetch_add(gcnt, 1u, __ATOMIC_ACQ_REL,
                                            __HIP_MEMORY_SCOPE_AGENT);
        if (p == 47u) {
            __hip_atomic_store(gcnt, 0u, __ATOMIC_RELAXED, __HIP_MEMORY_SCOPE_AGENT);
            unsigned q = __hip_atomic_fetch_add(ccnt, 1u, __ATOMIC_ACQ_REL,
                                                __HIP_MEMORY_SCOPE_AGENT);
            if (q == 7u) {
                __hip_atomic_store(ccnt, 0u, __ATOMIC_RELAXED, __HIP_MEMORY_SCOPE_AGENT);
                __hip_atomic_store(gen, target, __ATOMIC_RELEASE, __HIP_MEMORY_SCOPE_AGENT);
            } else {
                spin_gen(gen, target);
            }
        } else {
            spin_gen(gen, target);
        }
    }
    __syncthreads();
}

// ---- MFMA tile accumulate, KT=128: acc += A[MI*32 x Klen] * B[128 x Klen]^T ----
template<int MI>
__device__ __forceinline__ void macT(
    f32x4 (&acc)[MI][4],
    const ushort* __restrict__ A, int lda,
    const ushort* __restrict__ Bm, int ldb,
    int n0, int kbase, int Klen,
    ushort* As, ushort* Bs)
{
    const int NA = 2 * MI;
    const int tid = threadIdx.x;
    const int lane = tid & 63;
    const int w = tid >> 6;
    const int wm = (w >> 1) * (MI * 16);
    const int wn = (w & 1) * 64;
    const int fr = lane & 15;
    const int fk = (lane >> 4) * 8;

    int arow[NA], akc[NA];
    #pragma unroll
    for (int i = 0; i < NA; ++i) {
        int c = tid + i * 256;
        arow[i] = c >> 4; akc[i] = (c & 15) * 8;
    }
    int brow[8], bkc[8];
    #pragma unroll
    for (int i = 0; i < 8; ++i) {
        int c = tid + i * 256;
        brow[i] = c >> 4; bkc[i] = (c & 15) * 8;
    }

    const int nk = Klen / KT;
    bf16x8 ra[NA], rb[8];
    #pragma unroll
    for (int i = 0; i < NA; ++i)
        ra[i] = *(const bf16x8*)(A + (size_t)arow[i] * lda + kbase + akc[i]);
    #pragma unroll
    for (int i = 0; i < 8; ++i)
        rb[i] = *(const bf16x8*)(Bm + (size_t)(n0 + brow[i]) * ldb + kbase + bkc[i]);
    #pragma unroll
    for (int i = 0; i < NA; ++i)
        *(bf16x8*)(As + arow[i] * LROW + akc[i]) = ra[i];
    #pragma unroll
    for (int i = 0; i < 8; ++i)
        *(bf16x8*)(Bs + brow[i] * LROW + bkc[i]) = rb[i];
    __syncthreads();

    for (int kt = 0; kt < nk; ++kt) {
        if (kt + 1 < nk) {
            int kb = kbase + (kt + 1) * KT;
            #pragma unroll
            for (int i = 0; i < NA; ++i)
                ra[i] = *(const bf16x8*)(A + (size_t)arow[i] * lda + kb + akc[i]);
            #pragma unroll
            for (int i = 0; i < 8; ++i)
                rb[i] = *(const bf16x8*)(Bm + (size_t)(n0 + brow[i]) * ldb + kb + bkc[i]);
        }
        #pragma unroll
        for (int ks = 0; ks < 4; ++ks) {
            bf16x8 af[MI], bfv[4];
            const int ko = ks * 32 + fk;
            #pragma unroll
            for (int mi = 0; mi < MI; ++mi)
                af[mi] = *(const bf16x8*)(As + (wm + mi * 16 + fr) * LROW + ko);
            #pragma unroll
            for (int ni = 0; ni < 4; ++ni)
                bfv[ni] = *(const bf16x8*)(Bs + (wn + ni * 16 + fr) * LROW + ko);
            #pragma unroll
            for (int mi = 0; mi < MI; ++mi)
                #pragma unroll
                for (int ni = 0; ni < 4; ++ni)
                    acc[mi][ni] = __builtin_amdgcn_mfma_f32_16x16x32_bf16(
                        af[mi], bfv[ni], acc[mi][ni], 0, 0, 0);
        }
        __syncthreads();
        if (kt + 1 < nk) {
            #pragma unroll
            for (int i = 0; i < NA; ++i)
                *(bf16x8*)(As + arow[i] * LROW + akc[i]) = ra[i];
            #pragma unroll
            for (int i = 0; i < 8; ++i)
                *(bf16x8*)(Bs + brow[i] * LROW + bkc[i]) = rb[i];
            __syncthreads();
        }
    }
}

// ================= device-side phase blocks (shared by mega + fallback) ======

__device__ __forceinline__ void gi_block(
    int bid, const ushort* __restrict__ yE, const ushort* __restrict__ WcombT,
    ushort* __restrict__ gip, ushort* As, ushort* Bs)
{
    const int tid = threadIdx.x;
    const int lane = tid & 63, w = tid >> 6;
    const int fr = lane & 15, hi = lane >> 4;
    const int nt = bid >> 5, rem = bid & 31;
    const int mq = rem >> 3, z = rem & 7;
    const int wm = (w >> 1) * 16, wn = (w & 1) * 64;
    const int n0 = nt * 128;
    f32x4 acc[1][4];
    #pragma unroll
    for (int ni = 0; ni < 4; ++ni) acc[0][ni] = (f32x4){0.f,0.f,0.f,0.f};
    macT<1>(acc, yE + (size_t)mq * 32 * VP, VP, WcombT, VP,
            n0, z * 640, 640, As, Bs);
    ushort* C = gip + (size_t)z * (Bq * G3H) + (size_t)mq * 32 * G3H;
    #pragma unroll
    for (int ni = 0; ni < 4; ++ni) {
        int n = n0 + wn + ni * 16 + fr;
        #pragma unroll
        for (int r = 0; r < 4; ++r) {
            int m = wm + hi * 4 + r;
            C[(size_t)m * G3H + n] = f2bf(acc[0][ni][r]);
        }
    }
}

__device__ __forceinline__ void gh_block(
    int j, const ushort* __restrict__ hBsrc, const ushort* __restrict__ WhhB,
    ushort* __restrict__ ghp, ushort* As, ushort* Bs)
{
    const int tid = threadIdx.x;
    const int lane = tid & 63, w = tid >> 6;
    const int fr = lane & 15, hi = lane >> 4;
    const int nt = j >> 2, rem = j & 3;
    const int mh = rem >> 1, kc = rem & 1;
    const int n0 = nt * 128;
    const int wm = (w >> 1) * 32, wn = (w & 1) * 64;
    f32x4 acc[2][4];
    #pragma unroll
    for (int mi = 0; mi < 2; ++mi)
        #pragma unroll
        for (int ni = 0; ni < 4; ++ni) acc[mi][ni] = (f32x4){0.f,0.f,0.f,0.f};
    macT<2>(acc, hBsrc + (size_t)mh * 64 * Hq, Hq, WhhB, Hq,
            n0, kc * 256, 256, As, Bs);
    ushort* C = ghp + (size_t)kc * (Bq * G3H);
    #pragma unroll
    for (int mi = 0; mi < 2; ++mi)
        #pragma unroll
        for (int ni = 0; ni < 4; ++ni) {
            int n = n0 + wn + ni * 16 + fr;
            #pragma unroll
            for (int r = 0; r < 4; ++r) {
                int m = mh * 64 + wm + mi * 16 + hi * 4 + r;
                C[(size_t)m * G3H + n] = f2bf(acc[mi][ni][r]);
            }
        }
}

__device__ __forceinline__ void gates_block(
    int bid, const ushort* __restrict__ gip, const ushort* __restrict__ ghp,
    const float* __restrict__ b_ih, const float* __restrict__ b_hh,
    const float* __restrict__ h_old, const float* __restrict__ esumAll,
    float* __restrict__ h_new, ushort* __restrict__ hB_new, int t, float* sred)
{
    const int tid = threadIdx.x;
    const int e = bid * 256 + tid;   // 65536 total
    const int b = e >> 9, i = e & 511;
    if (t > 0) {
        if (tid < 40) sred[tid] = esumAll[(size_t)(t - 1) * 5120 + tid * 128 + b];
        __syncthreads();
        if (tid == 0) {
            float S = 0.f;
            #pragma unroll
            for (int nt = 0; nt < 40; ++nt) S += sred[nt];
            sred[63] = 1.0f / S;
        }
        __syncthreads();
    } else {
        if (tid == 0) sred[63] = 1.0f;
        __syncthreads();
    }
    const float invS = sred[63];
    __syncthreads();

    const size_t o = (size_t)b * G3H + i;
    float xr = 0.f, xz = 0.f, xn = 0.f;
    #pragma unroll
    for (int z = 0; z < 8; ++z) {
        const ushort* gp = gip + (size_t)z * (Bq * G3H) + o;
        xr += bf2f(gp[0]); xz += bf2f(gp[Hq]); xn += bf2f(gp[2 * Hq]);
    }
    xr = xr * invS + b_ih[i];
    xz = xz * invS + b_ih[Hq + i];
    xn = xn * invS + b_ih[2 * Hq + i];
    const ushort* h0p = ghp + o;
    const ushort* h1p = ghp + (size_t)(Bq * G3H) + o;
    float hr = b_hh[i] + bf2f(h0p[0]) + bf2f(h1p[0]);
    float hz = b_hh[Hq + i] + bf2f(h0p[Hq]) + bf2f(h1p[Hq]);
    float hn = b_hh[2 * Hq + i] + bf2f(h0p[2 * Hq]) + bf2f(h1p[2 * Hq]);
    float r = 1.f / (1.f + expf(-(xr + hr)));
    float zz = 1.f / (1.f + expf(-(xz + hz)));
    float nn = tanhf(xn + r * hn);
    float hv = (1.f - zz) * nn + zz * h_old[e];
    h_new[e] = hv;
    hB_new[e] = f2bf(hv);
}

__device__ __forceinline__ void logits_block(
    int bid, const ushort* __restrict__ hB, const ushort* __restrict__ WoutB,
    const float* __restrict__ b_out, const float* __restrict__ gum,
    const float* __restrict__ temp, float* __restrict__ out,
    ushort* __restrict__ yE, float* __restrict__ esumAll, int t,
    ushort* As, ushort* Bs)
{
    const int tid = threadIdx.x;
    const int lane = tid & 63, w = tid >> 6;
    const int fr = lane & 15, hi = lane >> 4;
    const int nt = bid % 40;
    const int mbase = (bid / 40) * 32;
    const int n0 = nt * 128;
    const int wm = (w >> 1) * 16, wn = (w & 1) * 64;
    const float inv_tau = 1.0f / temp[0];
    f32x4 acc[1][4];
    #pragma unroll
    for (int ni = 0; ni < 4; ++ni) acc[0][ni] = (f32x4){0.f,0.f,0.f,0.f};
    macT<1>(acc, hB + (size_t)mbase * Hq, Hq, WoutB, Hq, n0, 0, Hq, As, Bs);

    float psum[4] = {0.f, 0.f, 0.f, 0.f};
    #pragma unroll
    for (int ni = 0; ni < 4; ++ni) {
        int v = n0 + wn + ni * 16 + fr;
        bool valid = v < Vq;
        float bo = valid ? b_out[v] : 0.f;
        #pragma unroll
        for (int r = 0; r < 4; ++r) {
            int m = mbase + wm + hi * 4 + r;
            float ev = 0.f;
            if (valid) {
                float g = gum[(size_t)m * Vq + v];
                ev = expf((acc[0][ni][r] + bo + g) * inv_tau);
                out[(size_t)m * Tq * Vq + (size_t)t * Vq + v] = ev;
            }
            yE[(size_t)m * VP + v] = f2bf(ev);
            psum[r] += ev;
        }
    }
    float* redbuf = (float*)As;   // safe: macT ended with __syncthreads
    #pragma unroll
    for (int r = 0; r < 4; ++r) {
        float s = psum[r];
        s += __shfl_xor(s, 1); s += __shfl_xor(s, 2);
        s += __shfl_xor(s, 4); s += __shfl_xor(s, 8);
        if (fr == 0)
            redbuf[((wm + hi * 4 + r) << 1) | (wn >> 6)] = s;
    }
    __syncthreads();
    if (tid < 32)
        esumAll[(size_t)t * 5120 + n0 + mbase + tid]
            = redbuf[tid * 2] + redbuf[tid * 2 + 1];
}

__device__ __forceinline__ void norm2(
    int bpair, int tprev, float* __restrict__ out,
    const float* __restrict__ esumAll)
{
    const int tid = threadIdx.x;
    #pragma unroll
    for (int j = 0; j < 2; ++j) {
        int b = bpair * 2 + j;
        float S = 0.f;
        #pragma unroll 8
        for (int nt = 0; nt < 40; ++nt)
            S += esumAll[(size_t)tprev * 5120 + nt * 128 + b];
        float inv = 1.0f / S;
        float* orow = out + ((size_t)b * Tq + tprev) * Vq;
        #pragma unroll
        for (int i = 0; i < 20; ++i) {
            int v = tid + i * 256;
            if (v < Vq) orow[v] *= inv;
        }
    }
}

// ================= persistent mega-kernel (custom barrier) ===================
__global__ __launch_bounds__(256, 2) void k_mega(
    ushort* yE, const ushort* WcombT, ushort* hB, float* h,
    const ushort* WhhB, ushort* gip, ushort* ghp,
    const ushort* WoutB, const float* b_out, const float* gumbel,
    const float* temp, float* out, float* esumAll,
    const float* b_ih, const float* b_hh, unsigned* bar)
{
    __shared__ __align__(16) ushort As[64 * LROW];
    __shared__ __align__(16) ushort Bs[128 * LROW];
    const int bid = blockIdx.x;
    unsigned tgt = 0;

    // pre-phase: gh(0) from hB ping-pong slot 0 (written by k_wh0)
    if (bid < 48)
        gh_block(bid, hB, WhhB, ghp, As, Bs);
    gridbar(bar, ++tgt);

    for (int t = 0; t < Tq; ++t) {
        float* h_old = h + (size_t)(t & 1) * 65536;
        float* h_new = h + (size_t)((t + 1) & 1) * 65536;
        ushort* hB_new = hB + (size_t)((t + 1) & 1) * 65536;

        // P1: gi partials (all 384 blocks)
        gi_block(bid, yE, WcombT, gip, As, Bs);
        gridbar(bar, ++tgt);

        // P2: gates + norm(t-1)
        if (bid < 256)
            gates_block(bid, gip, ghp, b_ih, b_hh, h_old, esumAll,
                        h_new, hB_new, t, (float*)As);
        else if (bid < 320) {
            if (t > 0) norm2(bid - 256, t - 1, out, esumAll);
        }
        gridbar(bar, ++tgt);

        // P3: logits(t) + gh(t+1)
        if (bid < 160)
            logits_block(bid, hB_new, WoutB, b_out,
                         gumbel + (size_t)t * Bq * Vq, temp,
                         out, yE, esumAll, t, As, Bs);
        else if (bid < 208) {
            if (t + 1 < Tq)
                gh_block(bid - 160, hB_new, WhhB, ghp, As, Bs);
        }
        gridbar(bar, ++tgt);
    }

    // tail: normalize out[:, T-1, :]
    if (bid < 64)
        norm2(bid, Tq - 1, out, esumAll);
}

// ================= prep / wh0 / zero =========================================
__global__ __launch_bounds__(256) void k_prep(
    const float* __restrict__ W_ih, const float* __restrict__ W_hh,
    const float* __restrict__ W_out, const float* __restrict__ noise,
    const float* __restrict__ W_init, const float* __restrict__ emb,
    ushort* __restrict__ WihB, ushort* __restrict__ WhhB, ushort* __restrict__ WoutB,
    ushort* __restrict__ noiseB, ushort* __restrict__ WinitB,
    ushort* __restrict__ embB, ushort* __restrict__ yE)
{
    const int tg = blockIdx.x * 256 + threadIdx.x;
    const int NTH = gridDim.x * 256;
    for (int i = tg; i < G3H * Eq / 4; i += NTH) {
        float4 f = *(const float4*)(W_ih + (size_t)i * 4);
        *(ushort4*)(WihB + (size_t)i * 4) =
            make_ushort4(f2bf(f.x), f2bf(f.y), f2bf(f.z), f2bf(f.w));
    }
    for (int i = tg; i < G3H * Hq / 4; i += NTH) {
        float4 f = *(const float4*)(W_hh + (size_t)i * 4);
        *(ushort4*)(WhhB + (size_t)i * 4) =
            make_ushort4(f2bf(f.x), f2bf(f.y), f2bf(f.z), f2bf(f.w));
    }
    for (int i = tg; i < VP * (Hq / 4); i += NTH) {
        int v = i >> 7, h4 = (i & 127) << 2;
        ushort4 o = make_ushort4(0, 0, 0, 0);
        if (v < Vq) {
            float4 f = *(const float4*)(W_out + (size_t)v * Hq + h4);
            o = make_ushort4(f2bf(f.x), f2bf(f.y), f2bf(f.z), f2bf(f.w));
        }
        *(ushort4*)(WoutB + (size_t)v * Hq + h4) = o;
    }
    for (int i = tg; i < VP * (Eq / 4); i += NTH) {
        int v = i >> 6, e4 = (i & 63) << 2;
        ushort4 o = make_ushort4(0, 0, 0, 0);
        if (v < Vq) {
            float4 f = *(const float4*)(emb + (size_t)v * Eq + e4);
            o = make_ushort4(f2bf(f.x), f2bf(f.y), f2bf(f.z), f2bf(f.w));
        }
        *(ushort4*)(embB + (size_t)v * Eq + e4) = o;
    }
    for (int i = tg; i < Bq * Lq / 4; i += NTH) {
        float4 f = *(const float4*)(noise + (size_t)i * 4);
        *(ushort4*)(noiseB + (size_t)i * 4) =
            make_ushort4(f2bf(f.x), f2bf(f.y), f2bf(f.z), f2bf(f.w));
    }
    for (int i = tg; i < Hq * Lq / 4; i += NTH) {
        float4 f = *(const float4*)(W_init + (size_t)i * 4);
        *(ushort4*)(WinitB + (size_t)i * 4) =
            make_ushort4(f2bf(f.x), f2bf(f.y), f2bf(f.z), f2bf(f.w));
    }
    for (int i = tg; i < Bq * (VP / 4); i += NTH) {
        int v4 = i % (VP / 4);
        ushort4 o = (v4 == 0) ? make_ushort4(0x3F80, 0, 0, 0)
                              : make_ushort4(0, 0, 0, 0);
        *(ushort4*)(yE + (size_t)i * 4) = o;
    }
}

__global__ __launch_bounds__(256) void k_wh0(
    const ushort* __restrict__ WihB, const ushort* __restrict__ embB,
    const ushort* __restrict__ noiseB, const ushort* __restrict__ WinitB,
    const float* __restrict__ b_init,
    ushort* __restrict__ WcombT, float* __restrict__ h0, ushort* __restrict__ hB0)
{
    __shared__ __align__(16) ushort As[128 * LROW];
    __shared__ __align__(16) ushort Bs[128 * LROW];
    const int bid = blockIdx.x;
    const int lane = threadIdx.x & 63;
    const int w = threadIdx.x >> 6;
    const int wm = (w >> 1) * 64, wn = (w & 1) * 64;
    const int fr = lane & 15, hi = lane >> 4;
    f32x4 acc[4][4];
    #pragma unroll
    for (int mi = 0; mi < 4; ++mi)
        #pragma unroll
        for (int ni = 0; ni < 4; ++ni) acc[mi][ni] = (f32x4){0.f,0.f,0.f,0.f};
    if (bid < 480) {
        int mt = bid / 40, nt = bid % 40;
        macT<4>(acc, WihB + (size_t)mt * 128 * Eq, Eq, embB, Eq,
                nt * 128, 0, Eq, As, Bs);
        #pragma unroll
        for (int mi = 0; mi < 4; ++mi)
            #pragma unroll
            for (int ni = 0; ni < 4; ++ni) {
                int n = nt * 128 + wn + ni * 16 + fr;
                #pragma unroll
                for (int r = 0; r < 4; ++r) {
                    int m = mt * 128 + wm + mi * 16 + hi * 4 + r;
                    WcombT[(size_t)m * VP + n] = f2bf(acc[mi][ni][r]);
                }
            }
    } else {
        int n0 = (bid - 480) * 128;
        macT<4>(acc, noiseB, Lq, WinitB, Lq, n0, 0, Lq, As, Bs);
        #pragma unroll
        for (int mi = 0; mi < 4; ++mi)
            #pragma unroll
            for (int ni = 0; ni < 4; ++ni) {
                int n = n0 + wn + ni * 16 + fr;
                float bv = b_init[n];
                #pragma unroll
                for (int r = 0; r < 4; ++r) {
                    int m = wm + mi * 16 + hi * 4 + r;
                    float v = acc[mi][ni][r] + bv;
                    h0[(size_t)m * Hq + n] = v;
                    hB0[(size_t)m * Hq + n] = f2bf(v);
                }
            }
    }
}

__global__ void k_zero(unsigned* __restrict__ bar)
{
    if (threadIdx.x < 512) bar[threadIdx.x] = 0u;
}

// ================= fallback per-step kernels (non-cooperative path) ==========
__global__ __launch_bounds__(256) void k_gi_f(
    const ushort* __restrict__ yE, const ushort* __restrict__ WcombT,
    const ushort* __restrict__ hB_old, const ushort* __restrict__ WhhB,
    ushort* __restrict__ gip, ushort* __restrict__ ghp)
{
    __shared__ __align__(16) ushort As[64 * LROW];
    __shared__ __align__(16) ushort Bs[128 * LROW];
    if (blockIdx.x < 384)
        gi_block(blockIdx.x, yE, WcombT, gip, As, Bs);
    else
        gh_block(blockIdx.x - 384, hB_old, WhhB, ghp, As, Bs);
}

__global__ __launch_bounds__(256) void k_gates_f(
    const ushort* __restrict__ gip, const ushort* __restrict__ ghp,
    const float* __restrict__ b_ih, const float* __restrict__ b_hh,
    const float* __restrict__ h_old, const float* __restrict__ esumAll,
    float* __restrict__ h_new, ushort* __restrict__ hB_new, int t)
{
    __shared__ float sred[64];
    gates_block(blockIdx.x, gip, ghp, b_ih, b_hh, h_old, esumAll,
                h_new, hB_new, t, sred);
}

__global__ __launch_bounds__(256) void k_logits_f(
    const ushort* __restrict__ hB, const ushort* __restrict__ WoutB,
    const ushort* __restrict__ WhhB,
    const float* __restrict__ b_out, const float* __restrict__ gum,
    const float* __restrict__ temp,
    float* __restrict__ out, ushort* __restrict__ yE,
    float* __restrict__ esumAll, ushort* __restrict__ ghp, int t)
{
    __shared__ __align__(16) ushort As[64 * LROW];
    __shared__ __align__(16) ushort Bs[128 * LROW];
    const int bid = blockIdx.x;
    if (bid < 160)
        logits_block(bid, hB, WoutB, b_out, gum, temp, out, yE, esumAll, t,
                     As, Bs);
    else if (bid < 208) {
        if (t + 1 < Tq)
            gh_block(bid - 160, hB, WhhB, ghp, As, Bs);
    } else if (t > 0)
        norm2(bid - 208, t - 1, out, esumAll);
}

__global__ __launch_bounds__(256) void k_tail_f(
    float* __restrict__ out, const float* __restrict__ esumAll)
{
    norm2(blockIdx.x, Tq - 1, out, esumAll);
}

// ================= host ======================================================
extern "C" void kernel_launch(void* const* d_in, const int* in_sizes, int n_in,
                              void* d_out, int out_size, void* d_ws, size_t ws_size,
                              hipStream_t stream)
{
    const float* noise   = (const float*)d_in[0];
    const float* gumbel  = (const float*)d_in[1];
    const float* temp    = (const float*)d_in[2];
    const float* W_init  = (const float*)d_in[3];
    const float* b_init  = (const float*)d_in[4];
    const float* emb     = (const float*)d_in[5];
    const float* W_ih    = (const float*)d_in[6];
    const float* W_hh    = (const float*)d_in[7];
    const float* b_ih    = (const float*)d_in[8];
    const float* b_hh    = (const float*)d_in[9];
    const float* W_out   = (const float*)d_in[10];
    const float* b_out   = (const float*)d_in[11];
    float* out = (float*)d_out;

    float* fbase   = (float*)d_ws;
    float* h       = fbase;                       // 2 * 65536
    float* esumAll = h + 2 * 65536;               // 128 * 5120 = 655360
    ushort* ub     = (ushort*)(esumAll + 655360);
    ushort* gip    = ub;                          // 8 * 196608 = 1572864
    ushort* ghp    = gip + 1572864;               // 2 * 196608 = 393216
    ushort* embB   = ghp + 393216;                // 1310720
    ushort* WihB   = embB + 1310720;              // 393216
    ushort* WhhB   = WihB + 393216;               // 786432
    ushort* WoutB  = WhhB + 786432;               // 2621440
    ushort* WcombT = WoutB + 2621440;             // 7864320
    ushort* noiseB = WcombT + 7864320;            // 16384 (dead after k_wh0)
    ushort* WinitB = noiseB + 16384;              // 65536
    ushort* hB     = WinitB + 65536;              // 2 * 65536
    ushort* yE     = hB + 2 * 65536;              // 655360

    // barrier state: reuse noiseB region (only read by k_wh0, dead afterwards)
    unsigned* bar = (unsigned*)noiseB;

    k_prep<<<dim3(512), dim3(256), 0, stream>>>(
        W_ih, W_hh, W_out, noise, W_init, emb,
        WihB, WhhB, WoutB, noiseB, WinitB, embB, yE);
    k_wh0<<<dim3(484), dim3(256), 0, stream>>>(
        WihB, embB, noiseB, WinitB, b_init, WcombT, h, hB);
    k_zero<<<dim3(1), dim3(512), 0, stream>>>(bar);

    // persistent path: one kernel for the whole T loop (cooperative launch
    // only for the co-residency guarantee; sync is the custom gridbar)
    {
        void* margs[16];
        margs[0]  = (void*)&yE;      margs[1]  = (void*)&WcombT;
        margs[2]  = (void*)&hB;      margs[3]  = (void*)&h;
        margs[4]  = (void*)&WhhB;    margs[5]  = (void*)&gip;
        margs[6]  = (void*)&ghp;     margs[7]  = (void*)&WoutB;
        margs[8]  = (void*)&b_out;   margs[9]  = (void*)&gumbel;
        margs[10] = (void*)&temp;    margs[11] = (void*)&out;
        margs[12] = (void*)&esumAll; margs[13] = (void*)&b_ih;
        margs[14] = (void*)&b_hh;    margs[15] = (void*)&bar;
        hipError_t e = hipLaunchCooperativeKernel(
            (const void*)k_mega, dim3(384), dim3(256), margs, 0, stream);
        if (e == hipSuccess) return;
        (void)hipGetLastError();   // clear error state, fall back
    }

    // fallback: per-step launches (previous verified structure)
    for (int t = 0; t < Tq; ++t) {
        float* h_old = h + (size_t)(t & 1) * 65536;
        float* h_new = h + (size_t)((t + 1) & 1) * 65536;
        ushort* hB_old = hB + (size_t)(t & 1) * 65536;
        ushort* hB_new = hB + (size_t)((t + 1) & 1) * 65536;

        k_gi_f<<<dim3(t == 0 ? 432 : 384), dim3(256), 0, stream>>>(
            yE, WcombT, hB_old, WhhB, gip, ghp);
        k_gates_f<<<dim3(256), dim3(256), 0, stream>>>(
            gip, ghp, b_ih, b_hh, h_old, esumAll, h_new, hB_new, t);
        k_logits_f<<<dim3(272), dim3(256), 0, stream>>>(
            hB_new, WoutB, WhhB, b_out, gumbel + (size_t)t * Bq * Vq, temp,
            out, yE, esumAll, ghp, t);
    }
    k_tail_f<<<dim3(64), dim3(256), 0, stream>>>(out, esumAll);
}

// Round 4
// 7252.301 us; speedup vs baseline: 3.1173x; 1.5822x over previous
//
#include <hip/hip_runtime.h>
#include <math.h>

#define Bq 128
#define Tq 128
#define Vq 5000
#define VP 5120
#define Eq 256
#define Hq 512
#define Lq 128
#define G3H 1536
#define KT 128
#define LROW 136

typedef __attribute__((ext_vector_type(8))) short bf16x8;
typedef __attribute__((ext_vector_type(4))) float f32x4;

__device__ __forceinline__ ushort f2bf(float f) {
    union { float f; unsigned u; } v; v.f = f;
    unsigned r = (v.u + 0x7FFFu + ((v.u >> 16) & 1u)) >> 16;
    return (ushort)r;
}
__device__ __forceinline__ float bf2f(ushort s) {
    union { unsigned u; float f; } v; v.u = ((unsigned)s) << 16;
    return v.f;
}

// ---- MFMA tile accumulate, KT=128: acc += A[MI*32 x Klen] * B[128 x Klen]^T ----
template<int MI>
__device__ __forceinline__ void macT(
    f32x4 (&acc)[MI][4],
    const ushort* __restrict__ A, int lda,
    const ushort* __restrict__ Bm, int ldb,
    int n0, int kbase, int Klen,
    ushort* As, ushort* Bs)
{
    const int NA = 2 * MI;
    const int tid = threadIdx.x;
    const int lane = tid & 63;
    const int w = tid >> 6;
    const int wm = (w >> 1) * (MI * 16);
    const int wn = (w & 1) * 64;
    const int fr = lane & 15;
    const int fk = (lane >> 4) * 8;

    int arow[NA], akc[NA];
    #pragma unroll
    for (int i = 0; i < NA; ++i) {
        int c = tid + i * 256;
        arow[i] = c >> 4; akc[i] = (c & 15) * 8;
    }
    int brow[8], bkc[8];
    #pragma unroll
    for (int i = 0; i < 8; ++i) {
        int c = tid + i * 256;
        brow[i] = c >> 4; bkc[i] = (c & 15) * 8;
    }

    const int nk = Klen / KT;
    bf16x8 ra[NA], rb[8];
    #pragma unroll
    for (int i = 0; i < NA; ++i)
        ra[i] = *(const bf16x8*)(A + (size_t)arow[i] * lda + kbase + akc[i]);
    #pragma unroll
    for (int i = 0; i < 8; ++i)
        rb[i] = *(const bf16x8*)(Bm + (size_t)(n0 + brow[i]) * ldb + kbase + bkc[i]);
    #pragma unroll
    for (int i = 0; i < NA; ++i)
        *(bf16x8*)(As + arow[i] * LROW + akc[i]) = ra[i];
    #pragma unroll
    for (int i = 0; i < 8; ++i)
        *(bf16x8*)(Bs + brow[i] * LROW + bkc[i]) = rb[i];
    __syncthreads();

    for (int kt = 0; kt < nk; ++kt) {
        if (kt + 1 < nk) {
            int kb = kbase + (kt + 1) * KT;
            #pragma unroll
            for (int i = 0; i < NA; ++i)
                ra[i] = *(const bf16x8*)(A + (size_t)arow[i] * lda + kb + akc[i]);
            #pragma unroll
            for (int i = 0; i < 8; ++i)
                rb[i] = *(const bf16x8*)(Bm + (size_t)(n0 + brow[i]) * ldb + kb + bkc[i]);
        }
        #pragma unroll
        for (int ks = 0; ks < 4; ++ks) {
            bf16x8 af[MI], bfv[4];
            const int ko = ks * 32 + fk;
            #pragma unroll
            for (int mi = 0; mi < MI; ++mi)
                af[mi] = *(const bf16x8*)(As + (wm + mi * 16 + fr) * LROW + ko);
            #pragma unroll
            for (int ni = 0; ni < 4; ++ni)
                bfv[ni] = *(const bf16x8*)(Bs + (wn + ni * 16 + fr) * LROW + ko);
            #pragma unroll
            for (int mi = 0; mi < MI; ++mi)
                #pragma unroll
                for (int ni = 0; ni < 4; ++ni)
                    acc[mi][ni] = __builtin_amdgcn_mfma_f32_16x16x32_bf16(
                        af[mi], bfv[ni], acc[mi][ni], 0, 0, 0);
        }
        __syncthreads();
        if (kt + 1 < nk) {
            #pragma unroll
            for (int i = 0; i < NA; ++i)
                *(bf16x8*)(As + arow[i] * LROW + akc[i]) = ra[i];
            #pragma unroll
            for (int i = 0; i < 8; ++i)
                *(bf16x8*)(Bs + brow[i] * LROW + bkc[i]) = rb[i];
            __syncthreads();
        }
    }
}

// ================= device-side phase blocks ==================================

// gi partial: bid in [0,384): nt(12) x mq(4) x z(8); z in low bits -> per-XCD
// WcombT working set ~= 1.97 MB < 4 MB per-XCD L2.
__device__ __forceinline__ void gi_block(
    int bid, const ushort* __restrict__ yE, const ushort* __restrict__ WcombT,
    ushort* __restrict__ gip, ushort* As, ushort* Bs)
{
    const int tid = threadIdx.x;
    const int lane = tid & 63, w = tid >> 6;
    const int fr = lane & 15, hi = lane >> 4;
    const int nt = bid >> 5, rem = bid & 31;
    const int mq = rem >> 3, z = rem & 7;
    const int wm = (w >> 1) * 16, wn = (w & 1) * 64;
    const int n0 = nt * 128;
    f32x4 acc[1][4];
    #pragma unroll
    for (int ni = 0; ni < 4; ++ni) acc[0][ni] = (f32x4){0.f,0.f,0.f,0.f};
    macT<1>(acc, yE + (size_t)mq * 32 * VP, VP, WcombT, VP,
            n0, z * 640, 640, As, Bs);
    ushort* C = gip + (size_t)z * (Bq * G3H) + (size_t)mq * 32 * G3H;
    #pragma unroll
    for (int ni = 0; ni < 4; ++ni) {
        int n = n0 + wn + ni * 16 + fr;
        #pragma unroll
        for (int r = 0; r < 4; ++r) {
            int m = wm + hi * 4 + r;
            C[(size_t)m * G3H + n] = f2bf(acc[0][ni][r]);
        }
    }
}

// gh partial: j in [0,48): nt(12) x mh(2) x kc(2), MI=2
__device__ __forceinline__ void gh_block(
    int j, const ushort* __restrict__ hBsrc, const ushort* __restrict__ WhhB,
    ushort* __restrict__ ghp, ushort* As, ushort* Bs)
{
    const int tid = threadIdx.x;
    const int lane = tid & 63, w = tid >> 6;
    const int fr = lane & 15, hi = lane >> 4;
    const int nt = j >> 2, rem = j & 3;
    const int mh = rem >> 1, kc = rem & 1;
    const int n0 = nt * 128;
    const int wm = (w >> 1) * 32, wn = (w & 1) * 64;
    f32x4 acc[2][4];
    #pragma unroll
    for (int mi = 0; mi < 2; ++mi)
        #pragma unroll
        for (int ni = 0; ni < 4; ++ni) acc[mi][ni] = (f32x4){0.f,0.f,0.f,0.f};
    macT<2>(acc, hBsrc + (size_t)mh * 64 * Hq, Hq, WhhB, Hq,
            n0, kc * 256, 256, As, Bs);
    ushort* C = ghp + (size_t)kc * (Bq * G3H);
    #pragma unroll
    for (int mi = 0; mi < 2; ++mi)
        #pragma unroll
        for (int ni = 0; ni < 4; ++ni) {
            int n = n0 + wn + ni * 16 + fr;
            #pragma unroll
            for (int r = 0; r < 4; ++r) {
                int m = mh * 64 + wm + mi * 16 + hi * 4 + r;
                C[(size_t)m * G3H + n] = f2bf(acc[mi][ni][r]);
            }
        }
}

// normalize two output rows of step tprev
__device__ __forceinline__ void norm2(
    int bpair, int tprev, float* __restrict__ out,
    const float* __restrict__ esumAll)
{
    const int tid = threadIdx.x;
    #pragma unroll
    for (int j = 0; j < 2; ++j) {
        int b = bpair * 2 + j;
        float S = 0.f;
        #pragma unroll 8
        for (int nt = 0; nt < 40; ++nt)
            S += esumAll[(size_t)tprev * 5120 + nt * 128 + b];
        float inv = 1.0f / S;
        float* orow = out + ((size_t)b * Tq + tprev) * Vq;
        #pragma unroll
        for (int i = 0; i < 20; ++i) {
            int v = tid + i * 256;
            if (v < Vq) orow[v] *= inv;
        }
    }
}

// ================= per-step kernel 1: gi + gh(t) + norm(t-1) =================
__global__ __launch_bounds__(256) void k_s1(
    const ushort* __restrict__ yE, const ushort* __restrict__ WcombT,
    const ushort* __restrict__ hB_old, const ushort* __restrict__ WhhB,
    ushort* __restrict__ gip, ushort* __restrict__ ghp,
    float* __restrict__ out, const float* __restrict__ esumAll, int t)
{
    __shared__ __align__(16) ushort As[64 * LROW];
    __shared__ __align__(16) ushort Bs[128 * LROW];
    const int bid = blockIdx.x;
    if (bid < 384)
        gi_block(bid, yE, WcombT, gip, As, Bs);
    else if (bid < 432)
        gh_block(bid - 384, hB_old, WhhB, ghp, As, Bs);
    else if (t > 0)
        norm2(bid - 432, t - 1, out, esumAll);
}

// ================= per-step kernel 2: gates (8 producer blocks) =============
// ================= + logits GEMM (160 consumer blocks, flag handoff) ========
// bar[0]: master arrival counter (monotone, 8 per step).
// bar[32*(1+r)], r=0..7: replicated generation words (one cache line each).
__global__ __launch_bounds__(256) void k_gl(
    const ushort* __restrict__ gip, const ushort* __restrict__ ghp,
    const float* __restrict__ b_ih, const float* __restrict__ b_hh,
    const float* __restrict__ h_old, float* __restrict__ h_new,
    ushort* __restrict__ hB_new,
    const ushort* __restrict__ WoutB, const float* __restrict__ b_out,
    const float* __restrict__ gum, const float* __restrict__ temp,
    float* __restrict__ out, ushort* __restrict__ yE,
    float* __restrict__ esumAll, unsigned* __restrict__ bar, int t)
{
    __shared__ __align__(16) ushort As[32 * LROW];
    __shared__ __align__(16) ushort Bs[128 * LROW];
    __shared__ float invS_sh[16];
    const int tid = threadIdx.x;
    const int bid = blockIdx.x;

    if (bid < 8) {
        // ---- gates producer: rows b0..b0+16, all 512 h-dims ----
        const int b0 = bid * 16;
        if (t > 0) {
            if (tid < 16) {
                float S = 0.f;
                #pragma unroll 8
                for (int q = 0; q < 40; ++q)
                    S += esumAll[(size_t)(t - 1) * 5120 + q * 128 + (b0 + tid)];
                invS_sh[tid] = 1.0f / S;
            }
        } else if (tid < 16) {
            invS_sh[tid] = 1.0f;
        }
        __syncthreads();
        for (int k = 0; k < 32; ++k) {
            const int el = k * 256 + tid;       // 0..8191
            const int lb = el >> 9, i = el & 511;
            const int b = b0 + lb;
            const int e = b * 512 + i;
            const float invS = invS_sh[lb];
            const size_t o = (size_t)b * G3H + i;
            float xr = 0.f, xz = 0.f, xn = 0.f;
            #pragma unroll
            for (int z = 0; z < 8; ++z) {
                const ushort* gp = gip + (size_t)z * (Bq * G3H) + o;
                xr += bf2f(gp[0]); xz += bf2f(gp[Hq]); xn += bf2f(gp[2 * Hq]);
            }
            xr = xr * invS + b_ih[i];
            xz = xz * invS + b_ih[Hq + i];
            xn = xn * invS + b_ih[2 * Hq + i];
            const ushort* h0p = ghp + o;
            const ushort* h1p = ghp + (size_t)(Bq * G3H) + o;
            float hr = b_hh[i] + bf2f(h0p[0]) + bf2f(h1p[0]);
            float hz = b_hh[Hq + i] + bf2f(h0p[Hq]) + bf2f(h1p[Hq]);
            float hn = b_hh[2 * Hq + i] + bf2f(h0p[2 * Hq]) + bf2f(h1p[2 * Hq]);
            float r = 1.f / (1.f + expf(-(xr + hr)));
            float zz = 1.f / (1.f + expf(-(xz + hz)));
            float nn = tanhf(xn + r * hn);
            float hv = (1.f - zz) * nn + zz * h_old[e];
            h_new[e] = hv;
            hB_new[e] = f2bf(hv);
        }
        // publish: barrier drains this block's stores, then release-RMW
        // (one producer per XCD -> every XCD's L2 gets written back)
        __syncthreads();
        if (tid == 0) {
            unsigned r = __hip_atomic_fetch_add(bar, 1u, __ATOMIC_ACQ_REL,
                                                __HIP_MEMORY_SCOPE_AGENT);
            if (r == (unsigned)(8 * t + 7)) {
                #pragma unroll
                for (int q = 0; q < 8; ++q)
                    __hip_atomic_store(bar + 32 * (q + 1), (unsigned)(t + 1),
                                       __ATOMIC_RELEASE, __HIP_MEMORY_SCOPE_AGENT);
            }
        }
        return;
    }

    // ---- logits GEMM consumer ----
    const int gidx = bid - 8;
    const int nt = gidx % 40;
    const int mbase = (gidx / 40) * 32;
    // wait for gates completion (20 pollers per replica line)
    if (tid == 0) {
        unsigned* rep = bar + 32 * ((gidx & 7) + 1);
        while (__hip_atomic_load(rep, __ATOMIC_RELAXED,
                                 __HIP_MEMORY_SCOPE_AGENT) < (unsigned)(t + 1))
            __builtin_amdgcn_s_sleep(2);
        (void)__hip_atomic_load(rep, __ATOMIC_ACQUIRE, __HIP_MEMORY_SCOPE_AGENT);
    }
    __syncthreads();

    const int lane = tid & 63, w = tid >> 6;
    const int fr = lane & 15, hi = lane >> 4;
    const int n0 = nt * 128;
    const int wm = (w >> 1) * 16, wn = (w & 1) * 64;
    const float inv_tau = 1.0f / temp[0];
    f32x4 acc[1][4];
    #pragma unroll
    for (int ni = 0; ni < 4; ++ni) acc[0][ni] = (f32x4){0.f,0.f,0.f,0.f};
    macT<1>(acc, hB_new + (size_t)mbase * Hq, Hq, WoutB, Hq, n0, 0, Hq, As, Bs);

    float psum[4] = {0.f, 0.f, 0.f, 0.f};
    #pragma unroll
    for (int ni = 0; ni < 4; ++ni) {
        int v = n0 + wn + ni * 16 + fr;
        bool valid = v < Vq;
        float bo = valid ? b_out[v] : 0.f;
        #pragma unroll
        for (int r = 0; r < 4; ++r) {
            int m = mbase + wm + hi * 4 + r;
            float ev = 0.f;
            if (valid) {
                float g = gum[(size_t)m * Vq + v];
                ev = expf((acc[0][ni][r] + bo + g) * inv_tau);
                out[(size_t)m * Tq * Vq + (size_t)t * Vq + v] = ev;
            }
            yE[(size_t)m * VP + v] = f2bf(ev);
            psum[r] += ev;
        }
    }
    float* redbuf = (float*)As;   // safe: macT ended with __syncthreads
    #pragma unroll
    for (int r = 0; r < 4; ++r) {
        float s = psum[r];
        s += __shfl_xor(s, 1); s += __shfl_xor(s, 2);
        s += __shfl_xor(s, 4); s += __shfl_xor(s, 8);
        if (fr == 0)
            redbuf[((wm + hi * 4 + r) << 1) | (wn >> 6)] = s;
    }
    __syncthreads();
    if (tid < 32)
        esumAll[(size_t)t * 5120 + n0 + mbase + tid]
            = redbuf[tid * 2] + redbuf[tid * 2 + 1];
}

// ================= prep / wh0 / zero =========================================
__global__ __launch_bounds__(256) void k_prep(
    const float* __restrict__ W_ih, const float* __restrict__ W_hh,
    const float* __restrict__ W_out, const float* __restrict__ noise,
    const float* __restrict__ W_init, const float* __restrict__ emb,
    ushort* __restrict__ WihB, ushort* __restrict__ WhhB, ushort* __restrict__ WoutB,
    ushort* __restrict__ noiseB, ushort* __restrict__ WinitB,
    ushort* __restrict__ embB, ushort* __restrict__ yE)
{
    const int tg = blockIdx.x * 256 + threadIdx.x;
    const int NTH = gridDim.x * 256;
    for (int i = tg; i < G3H * Eq / 4; i += NTH) {
        float4 f = *(const float4*)(W_ih + (size_t)i * 4);
        *(ushort4*)(WihB + (size_t)i * 4) =
            make_ushort4(f2bf(f.x), f2bf(f.y), f2bf(f.z), f2bf(f.w));
    }
    for (int i = tg; i < G3H * Hq / 4; i += NTH) {
        float4 f = *(const float4*)(W_hh + (size_t)i * 4);
        *(ushort4*)(WhhB + (size_t)i * 4) =
            make_ushort4(f2bf(f.x), f2bf(f.y), f2bf(f.z), f2bf(f.w));
    }
    for (int i = tg; i < VP * (Hq / 4); i += NTH) {
        int v = i >> 7, h4 = (i & 127) << 2;
        ushort4 o = make_ushort4(0, 0, 0, 0);
        if (v < Vq) {
            float4 f = *(const float4*)(W_out + (size_t)v * Hq + h4);
            o = make_ushort4(f2bf(f.x), f2bf(f.y), f2bf(f.z), f2bf(f.w));
        }
        *(ushort4*)(WoutB + (size_t)v * Hq + h4) = o;
    }
    for (int i = tg; i < VP * (Eq / 4); i += NTH) {
        int v = i >> 6, e4 = (i & 63) << 2;
        ushort4 o = make_ushort4(0, 0, 0, 0);
        if (v < Vq) {
            float4 f = *(const float4*)(emb + (size_t)v * Eq + e4);
            o = make_ushort4(f2bf(f.x), f2bf(f.y), f2bf(f.z), f2bf(f.w));
        }
        *(ushort4*)(embB + (size_t)v * Eq + e4) = o;
    }
    for (int i = tg; i < Bq * Lq / 4; i += NTH) {
        float4 f = *(const float4*)(noise + (size_t)i * 4);
        *(ushort4*)(noiseB + (size_t)i * 4) =
            make_ushort4(f2bf(f.x), f2bf(f.y), f2bf(f.z), f2bf(f.w));
    }
    for (int i = tg; i < Hq * Lq / 4; i += NTH) {
        float4 f = *(const float4*)(W_init + (size_t)i * 4);
        *(ushort4*)(WinitB + (size_t)i * 4) =
            make_ushort4(f2bf(f.x), f2bf(f.y), f2bf(f.z), f2bf(f.w));
    }
    for (int i = tg; i < Bq * (VP / 4); i += NTH) {
        int v4 = i % (VP / 4);
        ushort4 o = (v4 == 0) ? make_ushort4(0x3F80, 0, 0, 0)
                              : make_ushort4(0, 0, 0, 0);
        *(ushort4*)(yE + (size_t)i * 4) = o;
    }
}

__global__ __launch_bounds__(256) void k_wh0(
    const ushort* __restrict__ WihB, const ushort* __restrict__ embB,
    const ushort* __restrict__ noiseB, const ushort* __restrict__ WinitB,
    const float* __restrict__ b_init,
    ushort* __restrict__ WcombT, float* __restrict__ h0, ushort* __restrict__ hB0)
{
    __shared__ __align__(16) ushort As[128 * LROW];
    __shared__ __align__(16) ushort Bs[128 * LROW];
    const int bid = blockIdx.x;
    const int lane = threadIdx.x & 63;
    const int w = threadIdx.x >> 6;
    const int wm = (w >> 1) * 64, wn = (w & 1) * 64;
    const int fr = lane & 15, hi = lane >> 4;
    f32x4 acc[4][4];
    #pragma unroll
    for (int mi = 0; mi < 4; ++mi)
        #pragma unroll
        for (int ni = 0; ni < 4; ++ni) acc[mi][ni] = (f32x4){0.f,0.f,0.f,0.f};
    if (bid < 480) {
        int mt = bid / 40, nt = bid % 40;
        macT<4>(acc, WihB + (size_t)mt * 128 * Eq, Eq, embB, Eq,
                nt * 128, 0, Eq, As, Bs);
        #pragma unroll
        for (int mi = 0; mi < 4; ++mi)
            #pragma unroll
            for (int ni = 0; ni < 4; ++ni) {
                int n = nt * 128 + wn + ni * 16 + fr;
                #pragma unroll
                for (int r = 0; r < 4; ++r) {
                    int m = mt * 128 + wm + mi * 16 + hi * 4 + r;
                    WcombT[(size_t)m * VP + n] = f2bf(acc[mi][ni][r]);
                }
            }
    } else {
        int n0 = (bid - 480) * 128;
        macT<4>(acc, noiseB, Lq, WinitB, Lq, n0, 0, Lq, As, Bs);
        #pragma unroll
        for (int mi = 0; mi < 4; ++mi)
            #pragma unroll
            for (int ni = 0; ni < 4; ++ni) {
                int n = n0 + wn + ni * 16 + fr;
                float bv = b_init[n];
                #pragma unroll
                for (int r = 0; r < 4; ++r) {
                    int m = wm + mi * 16 + hi * 4 + r;
                    float v = acc[mi][ni][r] + bv;
                    h0[(size_t)m * Hq + n] = v;
                    hB0[(size_t)m * Hq + n] = f2bf(v);
                }
            }
    }
}

__global__ void k_zero(unsigned* __restrict__ bar)
{
    if (threadIdx.x < 512) bar[threadIdx.x] = 0u;
}

// ---------- tail: normalize out[:, T-1, :] ----------
__global__ __launch_bounds__(256) void k_tail(
    float* __restrict__ out, const float* __restrict__ esumAll)
{
    norm2(blockIdx.x, Tq - 1, out, esumAll);
}

// ================= host ======================================================
extern "C" void kernel_launch(void* const* d_in, const int* in_sizes, int n_in,
                              void* d_out, int out_size, void* d_ws, size_t ws_size,
                              hipStream_t stream)
{
    const float* noise   = (const float*)d_in[0];
    const float* gumbel  = (const float*)d_in[1];
    const float* temp    = (const float*)d_in[2];
    const float* W_init  = (const float*)d_in[3];
    const float* b_init  = (const float*)d_in[4];
    const float* emb     = (const float*)d_in[5];
    const float* W_ih    = (const float*)d_in[6];
    const float* W_hh    = (const float*)d_in[7];
    const float* b_ih    = (const float*)d_in[8];
    const float* b_hh    = (const float*)d_in[9];
    const float* W_out   = (const float*)d_in[10];
    const float* b_out   = (const float*)d_in[11];
    float* out = (float*)d_out;

    float* fbase   = (float*)d_ws;
    float* h       = fbase;                       // 2 * 65536
    float* esumAll = h + 2 * 65536;               // 128 * 5120 = 655360
    ushort* ub     = (ushort*)(esumAll + 655360);
    ushort* gip    = ub;                          // 8 * 196608 = 1572864
    ushort* ghp    = gip + 1572864;               // 2 * 196608 = 393216
    ushort* embB   = ghp + 393216;                // 1310720
    ushort* WihB   = embB + 1310720;              // 393216
    ushort* WhhB   = WihB + 393216;               // 786432
    ushort* WoutB  = WhhB + 786432;               // 2621440
    ushort* WcombT = WoutB + 2621440;             // 7864320
    ushort* noiseB = WcombT + 7864320;            // 16384 (dead after k_wh0)
    ushort* WinitB = noiseB + 16384;              // 65536
    ushort* hB     = WinitB + 65536;              // 2 * 65536
    ushort* yE     = hB + 2 * 65536;              // 655360

    // handoff-flag state: reuse noiseB region (dead after k_wh0)
    unsigned* bar = (unsigned*)noiseB;

    k_prep<<<dim3(512), dim3(256), 0, stream>>>(
        W_ih, W_hh, W_out, noise, W_init, emb,
        WihB, WhhB, WoutB, noiseB, WinitB, embB, yE);
    k_wh0<<<dim3(484), dim3(256), 0, stream>>>(
        WihB, embB, noiseB, WinitB, b_init, WcombT, h, hB);
    k_zero<<<dim3(1), dim3(512), 0, stream>>>(bar);

    for (int t = 0; t < Tq; ++t) {
        float* h_old = h + (size_t)(t & 1) * 65536;
        float* h_new = h + (size_t)((t + 1) & 1) * 65536;
        ushort* hB_old = hB + (size_t)(t & 1) * 65536;
        ushort* hB_new = hB + (size_t)((t + 1) & 1) * 65536;

        k_s1<<<dim3(t == 0 ? 432 : 496), dim3(256), 0, stream>>>(
            yE, WcombT, hB_old, WhhB, gip, ghp, out, esumAll, t);
        k_gl<<<dim3(168), dim3(256), 0, stream>>>(
            gip, ghp, b_ih, b_hh, h_old, h_new, hB_new,
            WoutB, b_out, gumbel + (size_t)t * Bq * Vq, temp,
            out, yE, esumAll, bar, t);
    }
    k_tail<<<dim3(64), dim3(256), 0, stream>>>(out, esumAll);
}

// Round 5
// 6770.278 us; speedup vs baseline: 3.3392x; 1.0712x over previous
//
#include <hip/hip_runtime.h>
#include <math.h>

#define Bq 128
#define Tq 128
#define Vq 5000
#define VP 5120
#define Eq 256
#define Hq 512
#define Lq 128
#define G3H 1536
#define KT 128
#define LROW 136
#define HS 520   // hsh row stride (ushorts): 520*2B = 1040B == 4 (mod 32) dwords, same bank residue as LROW

typedef __attribute__((ext_vector_type(8))) short bf16x8;
typedef __attribute__((ext_vector_type(4))) float f32x4;

__device__ __forceinline__ ushort f2bf(float f) {
    union { float f; unsigned u; } v; v.f = f;
    unsigned r = (v.u + 0x7FFFu + ((v.u >> 16) & 1u)) >> 16;
    return (ushort)r;
}
__device__ __forceinline__ float bf2f(ushort s) {
    union { unsigned u; float f; } v; v.u = ((unsigned)s) << 16;
    return v.f;
}
__device__ __forceinline__ float lof(unsigned u) {
    union { unsigned x; float f; } v; v.x = u << 16; return v.f;
}
__device__ __forceinline__ float hif(unsigned u) {
    union { unsigned x; float f; } v; v.x = u & 0xFFFF0000u; return v.f;
}
__device__ __forceinline__ float rcpf(float x) { return __builtin_amdgcn_rcpf(x); }

// ---- MFMA tile accumulate, KT=128: acc += A[MI*32 x Klen] * B[128 x Klen]^T ----
template<int MI>
__device__ __forceinline__ void macT(
    f32x4 (&acc)[MI][4],
    const ushort* __restrict__ A, int lda,
    const ushort* __restrict__ Bm, int ldb,
    int n0, int kbase, int Klen,
    ushort* As, ushort* Bs)
{
    const int NA = 2 * MI;
    const int tid = threadIdx.x;
    const int lane = tid & 63;
    const int w = tid >> 6;
    const int wm = (w >> 1) * (MI * 16);
    const int wn = (w & 1) * 64;
    const int fr = lane & 15;
    const int fk = (lane >> 4) * 8;

    int arow[NA], akc[NA];
    #pragma unroll
    for (int i = 0; i < NA; ++i) {
        int c = tid + i * 256;
        arow[i] = c >> 4; akc[i] = (c & 15) * 8;
    }
    int brow[8], bkc[8];
    #pragma unroll
    for (int i = 0; i < 8; ++i) {
        int c = tid + i * 256;
        brow[i] = c >> 4; bkc[i] = (c & 15) * 8;
    }

    const int nk = Klen / KT;
    bf16x8 ra[NA], rb[8];
    #pragma unroll
    for (int i = 0; i < NA; ++i)
        ra[i] = *(const bf16x8*)(A + (size_t)arow[i] * lda + kbase + akc[i]);
    #pragma unroll
    for (int i = 0; i < 8; ++i)
        rb[i] = *(const bf16x8*)(Bm + (size_t)(n0 + brow[i]) * ldb + kbase + bkc[i]);
    #pragma unroll
    for (int i = 0; i < NA; ++i)
        *(bf16x8*)(As + arow[i] * LROW + akc[i]) = ra[i];
    #pragma unroll
    for (int i = 0; i < 8; ++i)
        *(bf16x8*)(Bs + brow[i] * LROW + bkc[i]) = rb[i];
    __syncthreads();

    for (int kt = 0; kt < nk; ++kt) {
        if (kt + 1 < nk) {
            int kb = kbase + (kt + 1) * KT;
            #pragma unroll
            for (int i = 0; i < NA; ++i)
                ra[i] = *(const bf16x8*)(A + (size_t)arow[i] * lda + kb + akc[i]);
            #pragma unroll
            for (int i = 0; i < 8; ++i)
                rb[i] = *(const bf16x8*)(Bm + (size_t)(n0 + brow[i]) * ldb + kb + bkc[i]);
        }
        #pragma unroll
        for (int ks = 0; ks < 4; ++ks) {
            bf16x8 af[MI], bfv[4];
            const int ko = ks * 32 + fk;
            #pragma unroll
            for (int mi = 0; mi < MI; ++mi)
                af[mi] = *(const bf16x8*)(As + (wm + mi * 16 + fr) * LROW + ko);
            #pragma unroll
            for (int ni = 0; ni < 4; ++ni)
                bfv[ni] = *(const bf16x8*)(Bs + (wn + ni * 16 + fr) * LROW + ko);
            #pragma unroll
            for (int mi = 0; mi < MI; ++mi)
                #pragma unroll
                for (int ni = 0; ni < 4; ++ni)
                    acc[mi][ni] = __builtin_amdgcn_mfma_f32_16x16x32_bf16(
                        af[mi], bfv[ni], acc[mi][ni], 0, 0, 0);
        }
        __syncthreads();
        if (kt + 1 < nk) {
            #pragma unroll
            for (int i = 0; i < NA; ++i)
                *(bf16x8*)(As + arow[i] * LROW + akc[i]) = ra[i];
            #pragma unroll
            for (int i = 0; i < 8; ++i)
                *(bf16x8*)(Bs + brow[i] * LROW + bkc[i]) = rb[i];
            __syncthreads();
        }
    }
}

// normalize two output rows of step tprev
__device__ __forceinline__ void norm2(
    int bpair, int tprev, float* __restrict__ out,
    const float* __restrict__ esumAll)
{
    const int tid = threadIdx.x;
    #pragma unroll
    for (int j = 0; j < 2; ++j) {
        int b = bpair * 2 + j;
        float S = 0.f;
        #pragma unroll 8
        for (int nt = 0; nt < 40; ++nt)
            S += esumAll[(size_t)tprev * 5120 + nt * 128 + b];
        float inv = 1.0f / S;
        float* orow = out + ((size_t)b * Tq + tprev) * Vq;
        #pragma unroll
        for (int i = 0; i < 20; ++i) {
            int v = tid + i * 256;
            if (v < Vq) orow[v] *= inv;
        }
    }
}

// ================= K_A: fused gates(t) + logits(t) + norm(t-1) ==============
// bid 0..159: (nt = bid%40, mq = bid/40). Same nt -> same XCD (40%8==0):
// WoutB slice stays L2-local. Each block recomputes gates for its own 32 rows
// (40x redundant VALU/L2 pass) and feeds the MFMA A-operand from LDS.
// bid 160..223: norm out[:, t-1, :].
__global__ __launch_bounds__(256) void k_A(
    const ushort* __restrict__ gip, const ushort* __restrict__ ghp,
    const float* __restrict__ b_ih, const float* __restrict__ b_hh,
    const float* __restrict__ h_old, float* __restrict__ h_new,
    ushort* __restrict__ hB_new,
    const ushort* __restrict__ WoutB, const float* __restrict__ b_out,
    const float* __restrict__ gum, const float* __restrict__ temp,
    float* __restrict__ out, ushort* __restrict__ yE,
    float* __restrict__ esumAll, int t)
{
    __shared__ __align__(16) ushort hsh[32 * HS];
    __shared__ __align__(16) ushort Bs[128 * LROW];
    __shared__ float invS_sh[32];
    const int tid = threadIdx.x;
    const int bid = blockIdx.x;

    if (bid >= 160) {
        if (t > 0) norm2(bid - 160, t - 1, out, esumAll);
        return;
    }
    const int nt = bid % 40;
    const int mq = bid / 40;
    const int b0 = mq * 32;
    const int ncol0 = nt * 128;

    // ---- B chunk-0 prefetch (independent of gates; hides HBM latency) ----
    int brow[8], bkc[8];
    #pragma unroll
    for (int i = 0; i < 8; ++i) {
        int c = tid + i * 256;
        brow[i] = c >> 4; bkc[i] = (c & 15) * 8;
    }
    bf16x8 rb[8];
    #pragma unroll
    for (int i = 0; i < 8; ++i)
        rb[i] = *(const bf16x8*)(WoutB + (size_t)(ncol0 + brow[i]) * Hq + bkc[i]);

    // ---- invS for rows b0..b0+31 ----
    if (tid < 32) {
        if (t > 0) {
            float S = 0.f;
            #pragma unroll 8
            for (int q = 0; q < 40; ++q)
                S += esumAll[(size_t)(t - 1) * 5120 + q * 128 + (b0 + tid)];
            invS_sh[tid] = 1.0f / S;
        } else {
            invS_sh[tid] = 1.0f;
        }
    }
    __syncthreads();

    // ---- gates for rows b0..b0+31 (pair-vectorized) ----
    const bool dw = (nt == 0);
    for (int k = 0; k < 32; ++k) {
        const int p = k * 256 + tid;        // pair index, all threads same row
        const int lb = p >> 8;              // 0..31
        const int i = (p & 255) * 2;        // even, 0..510
        const int b = b0 + lb;
        const float invS = invS_sh[lb];
        const size_t o = (size_t)b * G3H + i;
        float xr0=0.f,xr1=0.f,xz0=0.f,xz1=0.f,xn0=0.f,xn1=0.f;
        #pragma unroll
        for (int z = 0; z < 8; ++z) {
            const ushort* gp = gip + (size_t)z * (Bq * G3H) + o;
            unsigned ur = *(const unsigned*)(gp);
            unsigned uz = *(const unsigned*)(gp + Hq);
            unsigned un = *(const unsigned*)(gp + 2 * Hq);
            xr0 += lof(ur); xr1 += hif(ur);
            xz0 += lof(uz); xz1 += hif(uz);
            xn0 += lof(un); xn1 += hif(un);
        }
        float2 bir = *(const float2*)(b_ih + i);
        float2 biz = *(const float2*)(b_ih + Hq + i);
        float2 bin = *(const float2*)(b_ih + 2 * Hq + i);
        xr0 = xr0 * invS + bir.x;  xr1 = xr1 * invS + bir.y;
        xz0 = xz0 * invS + biz.x;  xz1 = xz1 * invS + biz.y;
        xn0 = xn0 * invS + bin.x;  xn1 = xn1 * invS + bin.y;
        const ushort* h0p = ghp + o;
        const ushort* h1p = ghp + (size_t)(Bq * G3H) + o;
        unsigned a0r = *(const unsigned*)(h0p);
        unsigned a0z = *(const unsigned*)(h0p + Hq);
        unsigned a0n = *(const unsigned*)(h0p + 2 * Hq);
        unsigned a1r = *(const unsigned*)(h1p);
        unsigned a1z = *(const unsigned*)(h1p + Hq);
        unsigned a1n = *(const unsigned*)(h1p + 2 * Hq);
        float2 bhr = *(const float2*)(b_hh + i);
        float2 bhz = *(const float2*)(b_hh + Hq + i);
        float2 bhn = *(const float2*)(b_hh + 2 * Hq + i);
        float hr0 = bhr.x + lof(a0r) + lof(a1r);
        float hr1 = bhr.y + hif(a0r) + hif(a1r);
        float hz0 = bhz.x + lof(a0z) + lof(a1z);
        float hz1 = bhz.y + hif(a0z) + hif(a1z);
        float hn0 = bhn.x + lof(a0n) + lof(a1n);
        float hn1 = bhn.y + hif(a0n) + hif(a1n);
        float r0 = rcpf(1.f + __expf(-(xr0 + hr0)));
        float r1 = rcpf(1.f + __expf(-(xr1 + hr1)));
        float z0 = rcpf(1.f + __expf(-(xz0 + hz0)));
        float z1 = rcpf(1.f + __expf(-(xz1 + hz1)));
        float e0 = __expf(2.f * (xn0 + r0 * hn0));
        float e1 = __expf(2.f * (xn1 + r1 * hn1));
        float nn0 = 1.f - 2.f * rcpf(e0 + 1.f);
        float nn1 = 1.f - 2.f * rcpf(e1 + 1.f);
        float2 ho = *(const float2*)(h_old + (size_t)b * Hq + i);
        float hv0 = (1.f - z0) * nn0 + z0 * ho.x;
        float hv1 = (1.f - z1) * nn1 + z1 * ho.y;
        if (dw)
            *(float2*)(h_new + (size_t)b * Hq + i) = make_float2(hv0, hv1);
        unsigned hb = (unsigned)f2bf(hv0) | ((unsigned)f2bf(hv1) << 16);
        if (dw)
            *(unsigned*)(hB_new + (size_t)b * Hq + i) = hb;
        *(unsigned*)(hsh + lb * HS + i) = hb;
    }
    __syncthreads();

    // ---- Bs chunk 0 write ----
    #pragma unroll
    for (int i = 0; i < 8; ++i)
        *(bf16x8*)(Bs + brow[i] * LROW + bkc[i]) = rb[i];
    __syncthreads();

    // ---- GEMM: C[32 x 128] = hsh[32 x 512] * WoutB[128 x 512]^T ----
    const int lane = tid & 63, w = tid >> 6;
    const int fr = lane & 15, hi = lane >> 4, fk = hi * 8;
    const int wm = (w >> 1) * 16, wn = (w & 1) * 64;
    f32x4 acc[4];
    #pragma unroll
    for (int ni = 0; ni < 4; ++ni) acc[ni] = (f32x4){0.f,0.f,0.f,0.f};
    for (int kt = 0; kt < 4; ++kt) {
        if (kt < 3) {
            int kb = (kt + 1) * KT;
            #pragma unroll
            for (int i = 0; i < 8; ++i)
                rb[i] = *(const bf16x8*)(WoutB + (size_t)(ncol0 + brow[i]) * Hq + kb + bkc[i]);
        }
        #pragma unroll
        for (int ks = 0; ks < 4; ++ks) {
            const int ko = ks * 32 + fk;
            bf16x8 af = *(const bf16x8*)(hsh + (wm + fr) * HS + kt * KT + ko);
            #pragma unroll
            for (int ni = 0; ni < 4; ++ni) {
                bf16x8 bfv = *(const bf16x8*)(Bs + (wn + ni * 16 + fr) * LROW + ko);
                acc[ni] = __builtin_amdgcn_mfma_f32_16x16x32_bf16(af, bfv, acc[ni], 0, 0, 0);
            }
        }
        __syncthreads();
        if (kt < 3) {
            #pragma unroll
            for (int i = 0; i < 8; ++i)
                *(bf16x8*)(Bs + brow[i] * LROW + bkc[i]) = rb[i];
            __syncthreads();
        }
    }

    // ---- epilogue: gumbel + exp -> out(unnorm), yE, esum[t] ----
    const float inv_tau = 1.0f / temp[0];
    float psum[4] = {0.f, 0.f, 0.f, 0.f};
    #pragma unroll
    for (int ni = 0; ni < 4; ++ni) {
        int v = ncol0 + wn + ni * 16 + fr;
        bool valid = v < Vq;
        float bo = valid ? b_out[v] : 0.f;
        #pragma unroll
        for (int r = 0; r < 4; ++r) {
            int m = b0 + wm + hi * 4 + r;
            float ev = 0.f;
            if (valid) {
                float g = gum[(size_t)m * Vq + v];
                ev = __expf((acc[ni][r] + bo + g) * inv_tau);
                out[(size_t)m * Tq * Vq + (size_t)t * Vq + v] = ev;
            }
            yE[(size_t)m * VP + v] = f2bf(ev);
            psum[r] += ev;
        }
    }
    float* redbuf = (float*)hsh;   // safe: unconditional __syncthreads above
    #pragma unroll
    for (int r = 0; r < 4; ++r) {
        float s = psum[r];
        s += __shfl_xor(s, 1); s += __shfl_xor(s, 2);
        s += __shfl_xor(s, 4); s += __shfl_xor(s, 8);
        if (fr == 0)
            redbuf[((wm + hi * 4 + r) << 1) | (wn >> 6)] = s;
    }
    __syncthreads();
    if (tid < 32)
        esumAll[(size_t)t * 5120 + ncol0 + b0 + tid]
            = redbuf[tid * 2] + redbuf[tid * 2 + 1];
}

// ================= K_B: gi(t+1) (192 blk MI=2) + gh(t+1) (48 blk) ===========
// gi: bid = nt*16 + mh*8 + z, z in low 3 bits -> per-XCD WcombT slice ~2 MB.
__global__ __launch_bounds__(256) void k_B(
    const ushort* __restrict__ yE, const ushort* __restrict__ WcombT,
    const ushort* __restrict__ hBsrc, const ushort* __restrict__ WhhB,
    ushort* __restrict__ gip, ushort* __restrict__ ghp)
{
    __shared__ __align__(16) ushort As[64 * LROW];
    __shared__ __align__(16) ushort Bs[128 * LROW];
    const int bid = blockIdx.x;
    const int lane = threadIdx.x & 63, w = threadIdx.x >> 6;
    const int fr = lane & 15, hi = lane >> 4;
    const int wm = (w >> 1) * 32, wn = (w & 1) * 64;
    f32x4 acc[2][4];
    #pragma unroll
    for (int mi = 0; mi < 2; ++mi)
        #pragma unroll
        for (int ni = 0; ni < 4; ++ni) acc[mi][ni] = (f32x4){0.f,0.f,0.f,0.f};
    if (bid < 192) {
        const int nt = bid >> 4, rem = bid & 15;
        const int mh = rem >> 3, z = rem & 7;
        const int n0 = nt * 128;
        macT<2>(acc, yE + (size_t)mh * 64 * VP, VP, WcombT, VP,
                n0, z * 640, 640, As, Bs);
        ushort* C = gip + (size_t)z * (Bq * G3H);
        #pragma unroll
        for (int mi = 0; mi < 2; ++mi)
            #pragma unroll
            for (int ni = 0; ni < 4; ++ni) {
                int n = n0 + wn + ni * 16 + fr;
                #pragma unroll
                for (int r = 0; r < 4; ++r) {
                    int m = mh * 64 + wm + mi * 16 + hi * 4 + r;
                    C[(size_t)m * G3H + n] = f2bf(acc[mi][ni][r]);
                }
            }
    } else {
        const int j = bid - 192;
        const int nt = j >> 2, rem = j & 3;
        const int mh = rem >> 1, kc = rem & 1;
        const int n0 = nt * 128;
        macT<2>(acc, hBsrc + (size_t)mh * 64 * Hq, Hq, WhhB, Hq,
                n0, kc * 256, 256, As, Bs);
        ushort* C = ghp + (size_t)kc * (Bq * G3H);
        #pragma unroll
        for (int mi = 0; mi < 2; ++mi)
            #pragma unroll
            for (int ni = 0; ni < 4; ++ni) {
                int n = n0 + wn + ni * 16 + fr;
                #pragma unroll
                for (int r = 0; r < 4; ++r) {
                    int m = mh * 64 + wm + mi * 16 + hi * 4 + r;
                    C[(size_t)m * G3H + n] = f2bf(acc[mi][ni][r]);
                }
            }
    }
}

// ================= prep / wh0 / tail =========================================
__global__ __launch_bounds__(256) void k_prep(
    const float* __restrict__ W_ih, const float* __restrict__ W_hh,
    const float* __restrict__ W_out, const float* __restrict__ noise,
    const float* __restrict__ W_init, const float* __restrict__ emb,
    ushort* __restrict__ WihB, ushort* __restrict__ WhhB, ushort* __restrict__ WoutB,
    ushort* __restrict__ noiseB, ushort* __restrict__ WinitB,
    ushort* __restrict__ embB, ushort* __restrict__ yE)
{
    const int tg = blockIdx.x * 256 + threadIdx.x;
    const int NTH = gridDim.x * 256;
    for (int i = tg; i < G3H * Eq / 4; i += NTH) {
        float4 f = *(const float4*)(W_ih + (size_t)i * 4);
        *(ushort4*)(WihB + (size_t)i * 4) =
            make_ushort4(f2bf(f.x), f2bf(f.y), f2bf(f.z), f2bf(f.w));
    }
    for (int i = tg; i < G3H * Hq / 4; i += NTH) {
        float4 f = *(const float4*)(W_hh + (size_t)i * 4);
        *(ushort4*)(WhhB + (size_t)i * 4) =
            make_ushort4(f2bf(f.x), f2bf(f.y), f2bf(f.z), f2bf(f.w));
    }
    for (int i = tg; i < VP * (Hq / 4); i += NTH) {
        int v = i >> 7, h4 = (i & 127) << 2;
        ushort4 o = make_ushort4(0, 0, 0, 0);
        if (v < Vq) {
            float4 f = *(const float4*)(W_out + (size_t)v * Hq + h4);
            o = make_ushort4(f2bf(f.x), f2bf(f.y), f2bf(f.z), f2bf(f.w));
        }
        *(ushort4*)(WoutB + (size_t)v * Hq + h4) = o;
    }
    for (int i = tg; i < VP * (Eq / 4); i += NTH) {
        int v = i >> 6, e4 = (i & 63) << 2;
        ushort4 o = make_ushort4(0, 0, 0, 0);
        if (v < Vq) {
            float4 f = *(const float4*)(emb + (size_t)v * Eq + e4);
            o = make_ushort4(f2bf(f.x), f2bf(f.y), f2bf(f.z), f2bf(f.w));
        }
        *(ushort4*)(embB + (size_t)v * Eq + e4) = o;
    }
    for (int i = tg; i < Bq * Lq / 4; i += NTH) {
        float4 f = *(const float4*)(noise + (size_t)i * 4);
        *(ushort4*)(noiseB + (size_t)i * 4) =
            make_ushort4(f2bf(f.x), f2bf(f.y), f2bf(f.z), f2bf(f.w));
    }
    for (int i = tg; i < Hq * Lq / 4; i += NTH) {
        float4 f = *(const float4*)(W_init + (size_t)i * 4);
        *(ushort4*)(WinitB + (size_t)i * 4) =
            make_ushort4(f2bf(f.x), f2bf(f.y), f2bf(f.z), f2bf(f.w));
    }
    for (int i = tg; i < Bq * (VP / 4); i += NTH) {
        int v4 = i % (VP / 4);
        ushort4 o = (v4 == 0) ? make_ushort4(0x3F80, 0, 0, 0)
                              : make_ushort4(0, 0, 0, 0);
        *(ushort4*)(yE + (size_t)i * 4) = o;
    }
}

__global__ __launch_bounds__(256) void k_wh0(
    const ushort* __restrict__ WihB, const ushort* __restrict__ embB,
    const ushort* __restrict__ noiseB, const ushort* __restrict__ WinitB,
    const float* __restrict__ b_init,
    ushort* __restrict__ WcombT, float* __restrict__ h0, ushort* __restrict__ hB0)
{
    __shared__ __align__(16) ushort As[128 * LROW];
    __shared__ __align__(16) ushort Bs[128 * LROW];
    const int bid = blockIdx.x;
    const int lane = threadIdx.x & 63;
    const int w = threadIdx.x >> 6;
    const int wm = (w >> 1) * 64, wn = (w & 1) * 64;
    const int fr = lane & 15, hi = lane >> 4;
    f32x4 acc[4][4];
    #pragma unroll
    for (int mi = 0; mi < 4; ++mi)
        #pragma unroll
        for (int ni = 0; ni < 4; ++ni) acc[mi][ni] = (f32x4){0.f,0.f,0.f,0.f};
    if (bid < 480) {
        int mt = bid / 40, nt = bid % 40;
        macT<4>(acc, WihB + (size_t)mt * 128 * Eq, Eq, embB, Eq,
                nt * 128, 0, Eq, As, Bs);
        #pragma unroll
        for (int mi = 0; mi < 4; ++mi)
            #pragma unroll
            for (int ni = 0; ni < 4; ++ni) {
                int n = nt * 128 + wn + ni * 16 + fr;
                #pragma unroll
                for (int r = 0; r < 4; ++r) {
                    int m = mt * 128 + wm + mi * 16 + hi * 4 + r;
                    WcombT[(size_t)m * VP + n] = f2bf(acc[mi][ni][r]);
                }
            }
    } else {
        int n0 = (bid - 480) * 128;
        macT<4>(acc, noiseB, Lq, WinitB, Lq, n0, 0, Lq, As, Bs);
        #pragma unroll
        for (int mi = 0; mi < 4; ++mi)
            #pragma unroll
            for (int ni = 0; ni < 4; ++ni) {
                int n = n0 + wn + ni * 16 + fr;
                float bv = b_init[n];
                #pragma unroll
                for (int r = 0; r < 4; ++r) {
                    int m = wm + mi * 16 + hi * 4 + r;
                    float v = acc[mi][ni][r] + bv;
                    h0[(size_t)m * Hq + n] = v;
                    hB0[(size_t)m * Hq + n] = f2bf(v);
                }
            }
    }
}

__global__ __launch_bounds__(256) void k_tail(
    float* __restrict__ out, const float* __restrict__ esumAll)
{
    norm2(blockIdx.x, Tq - 1, out, esumAll);
}

// ================= host ======================================================
extern "C" void kernel_launch(void* const* d_in, const int* in_sizes, int n_in,
                              void* d_out, int out_size, void* d_ws, size_t ws_size,
                              hipStream_t stream)
{
    const float* noise   = (const float*)d_in[0];
    const float* gumbel  = (const float*)d_in[1];
    const float* temp    = (const float*)d_in[2];
    const float* W_init  = (const float*)d_in[3];
    const float* b_init  = (const float*)d_in[4];
    const float* emb     = (const float*)d_in[5];
    const float* W_ih    = (const float*)d_in[6];
    const float* W_hh    = (const float*)d_in[7];
    const float* b_ih    = (const float*)d_in[8];
    const float* b_hh    = (const float*)d_in[9];
    const float* W_out   = (const float*)d_in[10];
    const float* b_out   = (const float*)d_in[11];
    float* out = (float*)d_out;

    float* fbase   = (float*)d_ws;
    float* h       = fbase;                       // 2 * 65536
    float* esumAll = h + 2 * 65536;               // 128 * 5120 = 655360
    ushort* ub     = (ushort*)(esumAll + 655360);
    ushort* gip    = ub;                          // 8 * 196608 = 1572864
    ushort* ghp    = gip + 1572864;               // 2 * 196608 = 393216
    ushort* embB   = ghp + 393216;                // 1310720
    ushort* WihB   = embB + 1310720;              // 393216
    ushort* WhhB   = WihB + 393216;               // 786432
    ushort* WoutB  = WhhB + 786432;               // 2621440
    ushort* WcombT = WoutB + 2621440;             // 7864320
    ushort* noiseB = WcombT + 7864320;            // 16384
    ushort* WinitB = noiseB + 16384;              // 65536
    ushort* hB     = WinitB + 65536;              // 2 * 65536
    ushort* yE     = hB + 2 * 65536;              // 655360

    k_prep<<<dim3(512), dim3(256), 0, stream>>>(
        W_ih, W_hh, W_out, noise, W_init, emb,
        WihB, WhhB, WoutB, noiseB, WinitB, embB, yE);
    k_wh0<<<dim3(484), dim3(256), 0, stream>>>(
        WihB, embB, noiseB, WinitB, b_init, WcombT, h, hB);

    // prologue: gi(0) from yE one-hot + gh(0) from hB slot 0
    k_B<<<dim3(240), dim3(256), 0, stream>>>(yE, WcombT, hB, WhhB, gip, ghp);

    for (int t = 0; t < Tq; ++t) {
        float* h_old = h + (size_t)(t & 1) * 65536;
        float* h_new = h + (size_t)((t + 1) & 1) * 65536;
        ushort* hB_new = hB + (size_t)((t + 1) & 1) * 65536;

        k_A<<<dim3(224), dim3(256), 0, stream>>>(
            gip, ghp, b_ih, b_hh, h_old, h_new, hB_new,
            WoutB, b_out, gumbel + (size_t)t * Bq * Vq, temp,
            out, yE, esumAll, t);
        if (t + 1 < Tq)
            k_B<<<dim3(240), dim3(256), 0, stream>>>(
                yE, WcombT, hB_new, WhhB, gip, ghp);
    }
    k_tail<<<dim3(64), dim3(256), 0, stream>>>(out, esumAll);
}

// Round 6
// 4103.533 us; speedup vs baseline: 5.5092x; 1.6499x over previous
//
#include <hip/hip_runtime.h>
#include <math.h>

#define Bq 128
#define Tq 128
#define Vq 5000
#define VP 5120
#define Eq 256
#define Hq 512
#define Lq 128
#define G3H 1536
#define KT 128
#define LROW 136

typedef __attribute__((ext_vector_type(8))) short bf16x8;
typedef __attribute__((ext_vector_type(4))) float f32x4;

__device__ __forceinline__ ushort f2bf(float f) {
    union { float f; unsigned u; } v; v.f = f;
    unsigned r = (v.u + 0x7FFFu + ((v.u >> 16) & 1u)) >> 16;
    return (ushort)r;
}
__device__ __forceinline__ float bf2f(ushort s) {
    union { unsigned u; float f; } v; v.u = ((unsigned)s) << 16;
    return v.f;
}
__device__ __forceinline__ float lof(unsigned u) {
    union { unsigned x; float f; } v; v.x = u << 16; return v.f;
}
__device__ __forceinline__ float hif(unsigned u) {
    union { unsigned x; float f; } v; v.x = u & 0xFFFF0000u; return v.f;
}
__device__ __forceinline__ float rcpf(float x) { return __builtin_amdgcn_rcpf(x); }

// ---- MFMA tile accumulate, KT=128: acc += A[MI*32 x Klen] * B[128 x Klen]^T ----
template<int MI>
__device__ __forceinline__ void macT(
    f32x4 (&acc)[MI][4],
    const ushort* __restrict__ A, int lda,
    const ushort* __restrict__ Bm, int ldb,
    int n0, int kbase, int Klen,
    ushort* As, ushort* Bs)
{
    const int NA = 2 * MI;
    const int tid = threadIdx.x;
    const int lane = tid & 63;
    const int w = tid >> 6;
    const int wm = (w >> 1) * (MI * 16);
    const int wn = (w & 1) * 64;
    const int fr = lane & 15;
    const int fk = (lane >> 4) * 8;

    int arow[NA], akc[NA];
    #pragma unroll
    for (int i = 0; i < NA; ++i) {
        int c = tid + i * 256;
        arow[i] = c >> 4; akc[i] = (c & 15) * 8;
    }
    int brow[8], bkc[8];
    #pragma unroll
    for (int i = 0; i < 8; ++i) {
        int c = tid + i * 256;
        brow[i] = c >> 4; bkc[i] = (c & 15) * 8;
    }

    const int nk = Klen / KT;
    bf16x8 ra[NA], rb[8];
    #pragma unroll
    for (int i = 0; i < NA; ++i)
        ra[i] = *(const bf16x8*)(A + (size_t)arow[i] * lda + kbase + akc[i]);
    #pragma unroll
    for (int i = 0; i < 8; ++i)
        rb[i] = *(const bf16x8*)(Bm + (size_t)(n0 + brow[i]) * ldb + kbase + bkc[i]);
    #pragma unroll
    for (int i = 0; i < NA; ++i)
        *(bf16x8*)(As + arow[i] * LROW + akc[i]) = ra[i];
    #pragma unroll
    for (int i = 0; i < 8; ++i)
        *(bf16x8*)(Bs + brow[i] * LROW + bkc[i]) = rb[i];
    __syncthreads();

    for (int kt = 0; kt < nk; ++kt) {
        if (kt + 1 < nk) {
            int kb = kbase + (kt + 1) * KT;
            #pragma unroll
            for (int i = 0; i < NA; ++i)
                ra[i] = *(const bf16x8*)(A + (size_t)arow[i] * lda + kb + akc[i]);
            #pragma unroll
            for (int i = 0; i < 8; ++i)
                rb[i] = *(const bf16x8*)(Bm + (size_t)(n0 + brow[i]) * ldb + kb + bkc[i]);
        }
        #pragma unroll
        for (int ks = 0; ks < 4; ++ks) {
            bf16x8 af[MI], bfv[4];
            const int ko = ks * 32 + fk;
            #pragma unroll
            for (int mi = 0; mi < MI; ++mi)
                af[mi] = *(const bf16x8*)(As + (wm + mi * 16 + fr) * LROW + ko);
            #pragma unroll
            for (int ni = 0; ni < 4; ++ni)
                bfv[ni] = *(const bf16x8*)(Bs + (wn + ni * 16 + fr) * LROW + ko);
            #pragma unroll
            for (int mi = 0; mi < MI; ++mi)
                #pragma unroll
                for (int ni = 0; ni < 4; ++ni)
                    acc[mi][ni] = __builtin_amdgcn_mfma_f32_16x16x32_bf16(
                        af[mi], bfv[ni], acc[mi][ni], 0, 0, 0);
        }
        __syncthreads();
        if (kt + 1 < nk) {
            #pragma unroll
            for (int i = 0; i < NA; ++i)
                *(bf16x8*)(As + arow[i] * LROW + akc[i]) = ra[i];
            #pragma unroll
            for (int i = 0; i < 8; ++i)
                *(bf16x8*)(Bs + brow[i] * LROW + bkc[i]) = rb[i];
            __syncthreads();
        }
    }
}

// gh partial: j in [0,48): nt(12) x mh(2) x kc(2), MI=2
__device__ __forceinline__ void gh_block(
    int j, const ushort* __restrict__ hBsrc, const ushort* __restrict__ WhhB,
    ushort* __restrict__ ghp, ushort* As, ushort* Bs)
{
    const int tid = threadIdx.x;
    const int lane = tid & 63, w = tid >> 6;
    const int fr = lane & 15, hi = lane >> 4;
    const int nt = j >> 2, rem = j & 3;
    const int mh = rem >> 1, kc = rem & 1;
    const int n0 = nt * 128;
    const int wm = (w >> 1) * 32, wn = (w & 1) * 64;
    f32x4 acc[2][4];
    #pragma unroll
    for (int mi = 0; mi < 2; ++mi)
        #pragma unroll
        for (int ni = 0; ni < 4; ++ni) acc[mi][ni] = (f32x4){0.f,0.f,0.f,0.f};
    macT<2>(acc, hBsrc + (size_t)mh * 64 * Hq, Hq, WhhB, Hq,
            n0, kc * 256, 256, As, Bs);
    ushort* C = ghp + (size_t)kc * (Bq * G3H);
    #pragma unroll
    for (int mi = 0; mi < 2; ++mi)
        #pragma unroll
        for (int ni = 0; ni < 4; ++ni) {
            int n = n0 + wn + ni * 16 + fr;
            #pragma unroll
            for (int r = 0; r < 4; ++r) {
                int m = mh * 64 + wm + mi * 16 + hi * 4 + r;
                C[(size_t)m * G3H + n] = f2bf(acc[mi][ni][r]);
            }
        }
}

// normalize two output rows of step tprev, esl = esum slice (5120 floats)
__device__ __forceinline__ void norm2s(
    int bpair, int tprev, float* __restrict__ out,
    const float* __restrict__ esl)
{
    const int tid = threadIdx.x;
    #pragma unroll
    for (int j = 0; j < 2; ++j) {
        int b = bpair * 2 + j;
        float S = 0.f;
        #pragma unroll 8
        for (int nt = 0; nt < 40; ++nt)
            S += esl[nt * 128 + b];
        float inv = 1.0f / S;
        float* orow = out + ((size_t)b * Tq + tprev) * Vq;
        #pragma unroll
        for (int i = 0; i < 20; ++i) {
            int v = tid + i * 256;
            if (v < Vq) orow[v] *= inv;
        }
    }
}

// ================= K_Q: gates(t) (128 blk, 1 row each) + norm(t-1) (64 blk) ==
// gates: thread tid handles element pair (b=bid, i=2*tid..2*tid+1).
// gi(t) = sum of 40 bf16 partials written by K_P(t-1) (zeros at t=0).
__global__ __launch_bounds__(256) void k_Q(
    const ushort* __restrict__ giP, const ushort* __restrict__ ghp,
    const float* __restrict__ b_ih, const float* __restrict__ b_hh,
    const float* __restrict__ h_old, const float* __restrict__ esumPrev,
    float* __restrict__ h_new, ushort* __restrict__ hB_new,
    float* __restrict__ out, int t)
{
    const int bid = blockIdx.x;
    const int tid = threadIdx.x;
    if (bid >= 128) {
        if (t > 0) norm2s(bid - 128, t - 1, out, esumPrev);
        return;
    }
    const int b = bid;
    float invS = 1.0f;
    if (t > 0) {
        float S = 0.f;
        #pragma unroll 8
        for (int q = 0; q < 40; ++q) S += esumPrev[q * 128 + b];
        invS = 1.0f / S;
    }
    const int i = tid * 2;                 // 0..510
    const size_t o = (size_t)b * G3H + i;
    float xr0=0.f,xr1=0.f,xz0=0.f,xz1=0.f,xn0=0.f,xn1=0.f;
    #pragma unroll 8
    for (int z = 0; z < 40; ++z) {
        const ushort* gp = giP + (size_t)z * (Bq * G3H) + o;
        unsigned ur = *(const unsigned*)(gp);
        unsigned uz = *(const unsigned*)(gp + Hq);
        unsigned un = *(const unsigned*)(gp + 2 * Hq);
        xr0 += lof(ur); xr1 += hif(ur);
        xz0 += lof(uz); xz1 += hif(uz);
        xn0 += lof(un); xn1 += hif(un);
    }
    float2 bir = *(const float2*)(b_ih + i);
    float2 biz = *(const float2*)(b_ih + Hq + i);
    float2 bin = *(const float2*)(b_ih + 2 * Hq + i);
    xr0 = xr0 * invS + bir.x;  xr1 = xr1 * invS + bir.y;
    xz0 = xz0 * invS + biz.x;  xz1 = xz1 * invS + biz.y;
    xn0 = xn0 * invS + bin.x;  xn1 = xn1 * invS + bin.y;
    const ushort* h0p = ghp + o;
    const ushort* h1p = ghp + (size_t)(Bq * G3H) + o;
    unsigned a0r = *(const unsigned*)(h0p);
    unsigned a0z = *(const unsigned*)(h0p + Hq);
    unsigned a0n = *(const unsigned*)(h0p + 2 * Hq);
    unsigned a1r = *(const unsigned*)(h1p);
    unsigned a1z = *(const unsigned*)(h1p + Hq);
    unsigned a1n = *(const unsigned*)(h1p + 2 * Hq);
    float2 bhr = *(const float2*)(b_hh + i);
    float2 bhz = *(const float2*)(b_hh + Hq + i);
    float2 bhn = *(const float2*)(b_hh + 2 * Hq + i);
    float hr0 = bhr.x + lof(a0r) + lof(a1r);
    float hr1 = bhr.y + hif(a0r) + hif(a1r);
    float hz0 = bhz.x + lof(a0z) + lof(a1z);
    float hz1 = bhz.y + hif(a0z) + hif(a1z);
    float hn0 = bhn.x + lof(a0n) + lof(a1n);
    float hn1 = bhn.y + hif(a0n) + hif(a1n);
    float r0 = rcpf(1.f + __expf(-(xr0 + hr0)));
    float r1 = rcpf(1.f + __expf(-(xr1 + hr1)));
    float z0 = rcpf(1.f + __expf(-(xz0 + hz0)));
    float z1 = rcpf(1.f + __expf(-(xz1 + hz1)));
    float e0 = __expf(2.f * (xn0 + r0 * hn0));
    float e1 = __expf(2.f * (xn1 + r1 * hn1));
    float nn0 = 1.f - 2.f * rcpf(e0 + 1.f);
    float nn1 = 1.f - 2.f * rcpf(e1 + 1.f);
    float2 ho = *(const float2*)(h_old + (size_t)b * Hq + i);
    float hv0 = (1.f - z0) * nn0 + z0 * ho.x;
    float hv1 = (1.f - z1) * nn1 + z1 * ho.y;
    *(float2*)(h_new + (size_t)b * Hq + i) = make_float2(hv0, hv1);
    unsigned hb = (unsigned)f2bf(hv0) | ((unsigned)f2bf(hv1) << 16);
    *(unsigned*)(hB_new + (size_t)b * Hq + i) = hb;
}

// ================= K_P: logits(t) + gi(t+1) partial (160 blk) + gh(t+1) (48) =
// Block (nt=bid%40, mq=bid/40): blocks sharing nt differ by 40 (40%8==0 -> same
// XCD): WoutB/WcombT nt-slices stay L2-local. After the logits epilogue, the
// block's unnormalized-e tile (32 rows x 128 vocab) sits in LDS and is
// multiplied into WcombT rows [0,1536) cols [nt*128,+128) -> gi partial z=nt.
__global__ __launch_bounds__(256) void k_P(
    const ushort* __restrict__ hBt, const ushort* __restrict__ WoutB,
    const ushort* __restrict__ WhhB, const ushort* __restrict__ WcombT,
    const float* __restrict__ b_out, const float* __restrict__ gum,
    const float* __restrict__ temp, float* __restrict__ out,
    float* __restrict__ esumCur, ushort* __restrict__ giP,
    ushort* __restrict__ ghp, int t)
{
    __shared__ __align__(16) ushort As[64 * LROW];
    __shared__ __align__(16) ushort Bs[128 * LROW];
    const int tid = threadIdx.x, bid = blockIdx.x;
    const int lane = tid & 63, w = tid >> 6;
    const int fr = lane & 15, hi = lane >> 4, fk = hi * 8;

    if (bid >= 160) {
        if (t + 1 < Tq)
            gh_block(bid - 160, hBt, WhhB, ghp, As, Bs);
        return;
    }
    const int nt = bid % 40, mq = bid / 40;
    const int b0 = mq * 32, ncol0 = nt * 128;
    const int wm = (w >> 1) * 16, wn = (w & 1) * 64;

    // ---- logits GEMM: C[32x128] = hB[32x512] * WoutB[128x512]^T ----
    f32x4 acc[1][4];
    #pragma unroll
    for (int ni = 0; ni < 4; ++ni) acc[0][ni] = (f32x4){0.f,0.f,0.f,0.f};
    macT<1>(acc, hBt + (size_t)b0 * Hq, Hq, WoutB, Hq, ncol0, 0, Hq, As, Bs);

    // ---- epilogue: gumbel+exp -> out(unnorm), yt tile (LDS), esum ----
    const float inv_tau = 1.0f / temp[0];
    float psum[4] = {0.f, 0.f, 0.f, 0.f};
    #pragma unroll
    for (int ni = 0; ni < 4; ++ni) {
        int v = ncol0 + wn + ni * 16 + fr;
        bool valid = v < Vq;
        float bo = valid ? b_out[v] : 0.f;
        #pragma unroll
        for (int r = 0; r < 4; ++r) {
            int ml = wm + hi * 4 + r;
            int m = b0 + ml;
            float ev = 0.f;
            if (valid) {
                float g = gum[(size_t)m * Vq + v];
                ev = __expf((acc[0][ni][r] + bo + g) * inv_tau);
                out[(size_t)m * Tq * Vq + (size_t)t * Vq + v] = ev;
            }
            As[ml * LROW + (wn + ni * 16 + fr)] = f2bf(ev);   // yt tile
            psum[r] += ev;
        }
    }
    float* redbuf = (float*)Bs;   // Bs free after macT's final barrier
    #pragma unroll
    for (int r = 0; r < 4; ++r) {
        float s = psum[r];
        s += __shfl_xor(s, 1); s += __shfl_xor(s, 2);
        s += __shfl_xor(s, 4); s += __shfl_xor(s, 8);
        if (fr == 0)
            redbuf[((wm + hi * 4 + r) << 1) | (wn >> 6)] = s;
    }
    __syncthreads();
    if (tid < 32)
        esumCur[ncol0 + b0 + tid] = redbuf[tid * 2] + redbuf[tid * 2 + 1];

    // ---- gi(t+1) partial: P[32x1536] = yt[32x128] * WcombT[1536x128@ncol0]^T
    if (t + 1 >= Tq) return;
    int brow[8], bkc[8];
    #pragma unroll
    for (int i = 0; i < 8; ++i) {
        int c = tid + i * 256;
        brow[i] = c >> 4; bkc[i] = (c & 15) * 8;
    }
    bf16x8 rb2[8];
    #pragma unroll
    for (int i = 0; i < 8; ++i)
        rb2[i] = *(const bf16x8*)(WcombT + (size_t)brow[i] * VP + ncol0 + bkc[i]);
    ushort* Pbase = giP + (size_t)nt * (Bq * G3H) + (size_t)b0 * G3H;
    for (int jt = 0; jt < 12; ++jt) {
        __syncthreads();                    // protect Bs (redbuf reads / prev MFMA)
        #pragma unroll
        for (int i = 0; i < 8; ++i)
            *(bf16x8*)(Bs + brow[i] * LROW + bkc[i]) = rb2[i];
        __syncthreads();
        if (jt + 1 < 12) {
            #pragma unroll
            for (int i = 0; i < 8; ++i)
                rb2[i] = *(const bf16x8*)(WcombT +
                    (size_t)((jt + 1) * 128 + brow[i]) * VP + ncol0 + bkc[i]);
        }
        f32x4 pac[4];
        #pragma unroll
        for (int ni = 0; ni < 4; ++ni) pac[ni] = (f32x4){0.f,0.f,0.f,0.f};
        #pragma unroll
        for (int ks = 0; ks < 4; ++ks) {
            const int ko = ks * 32 + fk;
            bf16x8 af = *(const bf16x8*)(As + (wm + fr) * LROW + ko);
            #pragma unroll
            for (int ni = 0; ni < 4; ++ni) {
                bf16x8 bv = *(const bf16x8*)(Bs + (wn + ni * 16 + fr) * LROW + ko);
                pac[ni] = __builtin_amdgcn_mfma_f32_16x16x32_bf16(af, bv, pac[ni], 0, 0, 0);
            }
        }
        ushort* P = Pbase + jt * 128;
        #pragma unroll
        for (int ni = 0; ni < 4; ++ni) {
            int jl = wn + ni * 16 + fr;
            #pragma unroll
            for (int r = 0; r < 4; ++r) {
                int ml = wm + hi * 4 + r;
                P[(size_t)ml * G3H + jl] = f2bf(pac[ni][r]);
            }
        }
    }
}

// ================= prep / wh0 / gh0+zero / tail ==============================
__global__ __launch_bounds__(256) void k_prep(
    const float* __restrict__ W_ih, const float* __restrict__ W_hh,
    const float* __restrict__ W_out, const float* __restrict__ noise,
    const float* __restrict__ W_init, const float* __restrict__ emb,
    ushort* __restrict__ WihB, ushort* __restrict__ WhhB, ushort* __restrict__ WoutB,
    ushort* __restrict__ noiseB, ushort* __restrict__ WinitB,
    ushort* __restrict__ embB)
{
    const int tg = blockIdx.x * 256 + threadIdx.x;
    const int NTH = gridDim.x * 256;
    for (int i = tg; i < G3H * Eq / 4; i += NTH) {
        float4 f = *(const float4*)(W_ih + (size_t)i * 4);
        *(ushort4*)(WihB + (size_t)i * 4) =
            make_ushort4(f2bf(f.x), f2bf(f.y), f2bf(f.z), f2bf(f.w));
    }
    for (int i = tg; i < G3H * Hq / 4; i += NTH) {
        float4 f = *(const float4*)(W_hh + (size_t)i * 4);
        *(ushort4*)(WhhB + (size_t)i * 4) =
            make_ushort4(f2bf(f.x), f2bf(f.y), f2bf(f.z), f2bf(f.w));
    }
    for (int i = tg; i < VP * (Hq / 4); i += NTH) {
        int v = i >> 7, h4 = (i & 127) << 2;
        ushort4 o = make_ushort4(0, 0, 0, 0);
        if (v < Vq) {
            float4 f = *(const float4*)(W_out + (size_t)v * Hq + h4);
            o = make_ushort4(f2bf(f.x), f2bf(f.y), f2bf(f.z), f2bf(f.w));
        }
        *(ushort4*)(WoutB + (size_t)v * Hq + h4) = o;
    }
    for (int i = tg; i < VP * (Eq / 4); i += NTH) {
        int v = i >> 6, e4 = (i & 63) << 2;
        ushort4 o = make_ushort4(0, 0, 0, 0);
        if (v < Vq) {
            float4 f = *(const float4*)(emb + (size_t)v * Eq + e4);
            o = make_ushort4(f2bf(f.x), f2bf(f.y), f2bf(f.z), f2bf(f.w));
        }
        *(ushort4*)(embB + (size_t)v * Eq + e4) = o;
    }
    for (int i = tg; i < Bq * Lq / 4; i += NTH) {
        float4 f = *(const float4*)(noise + (size_t)i * 4);
        *(ushort4*)(noiseB + (size_t)i * 4) =
            make_ushort4(f2bf(f.x), f2bf(f.y), f2bf(f.z), f2bf(f.w));
    }
    for (int i = tg; i < Hq * Lq / 4; i += NTH) {
        float4 f = *(const float4*)(W_init + (size_t)i * 4);
        *(ushort4*)(WinitB + (size_t)i * 4) =
            make_ushort4(f2bf(f.x), f2bf(f.y), f2bf(f.z), f2bf(f.w));
    }
}

__global__ __launch_bounds__(256) void k_wh0(
    const ushort* __restrict__ WihB, const ushort* __restrict__ embB,
    const ushort* __restrict__ noiseB, const ushort* __restrict__ WinitB,
    const float* __restrict__ b_init,
    ushort* __restrict__ WcombT, float* __restrict__ h0, ushort* __restrict__ hB0)
{
    __shared__ __align__(16) ushort As[128 * LROW];
    __shared__ __align__(16) ushort Bs[128 * LROW];
    const int bid = blockIdx.x;
    const int lane = threadIdx.x & 63;
    const int w = threadIdx.x >> 6;
    const int wm = (w >> 1) * 64, wn = (w & 1) * 64;
    const int fr = lane & 15, hi = lane >> 4;
    f32x4 acc[4][4];
    #pragma unroll
    for (int mi = 0; mi < 4; ++mi)
        #pragma unroll
        for (int ni = 0; ni < 4; ++ni) acc[mi][ni] = (f32x4){0.f,0.f,0.f,0.f};
    if (bid < 480) {
        int mt = bid / 40, nt = bid % 40;
        macT<4>(acc, WihB + (size_t)mt * 128 * Eq, Eq, embB, Eq,
                nt * 128, 0, Eq, As, Bs);
        #pragma unroll
        for (int mi = 0; mi < 4; ++mi)
            #pragma unroll
            for (int ni = 0; ni < 4; ++ni) {
                int n = nt * 128 + wn + ni * 16 + fr;
                #pragma unroll
                for (int r = 0; r < 4; ++r) {
                    int m = mt * 128 + wm + mi * 16 + hi * 4 + r;
                    WcombT[(size_t)m * VP + n] = f2bf(acc[mi][ni][r]);
                }
            }
    } else {
        int n0 = (bid - 480) * 128;
        macT<4>(acc, noiseB, Lq, WinitB, Lq, n0, 0, Lq, As, Bs);
        #pragma unroll
        for (int mi = 0; mi < 4; ++mi)
            #pragma unroll
            for (int ni = 0; ni < 4; ++ni) {
                int n = n0 + wn + ni * 16 + fr;
                float bv = b_init[n];
                #pragma unroll
                for (int r = 0; r < 4; ++r) {
                    int m = wm + mi * 16 + hi * 4 + r;
                    float v = acc[mi][ni][r] + bv;
                    h0[(size_t)m * Hq + n] = v;
                    hB0[(size_t)m * Hq + n] = f2bf(v);
                }
            }
    }
}

// gh(0) (48 blk) + zero giP (192 blk). Runs after k_wh0 (embB etc. dead).
__global__ __launch_bounds__(256) void k_gh0(
    const ushort* __restrict__ hB0, const ushort* __restrict__ WhhB,
    ushort* __restrict__ ghp, ushort* __restrict__ giP)
{
    __shared__ __align__(16) ushort As[64 * LROW];
    __shared__ __align__(16) ushort Bs[128 * LROW];
    const int bid = blockIdx.x;
    if (bid < 48) {
        gh_block(bid, hB0, WhhB, ghp, As, Bs);
    } else {
        const int zb = bid - 48;                 // 0..191
        ushort4* p = (ushort4*)giP;
        const int total = 40 * Bq * G3H / 4;     // 1,966,080 ushort4
        const int per = total / 192;             // 10240
        int base = zb * per + threadIdx.x;
        #pragma unroll 8
        for (int k = 0; k < 40; ++k)
            p[base + k * 256] = make_ushort4(0, 0, 0, 0);
    }
}

__global__ __launch_bounds__(256) void k_tail(
    float* __restrict__ out, const float* __restrict__ esl)
{
    norm2s(blockIdx.x, Tq - 1, out, esl);
}

// ================= host ======================================================
extern "C" void kernel_launch(void* const* d_in, const int* in_sizes, int n_in,
                              void* d_out, int out_size, void* d_ws, size_t ws_size,
                              hipStream_t stream)
{
    const float* noise   = (const float*)d_in[0];
    const float* gumbel  = (const float*)d_in[1];
    const float* temp    = (const float*)d_in[2];
    const float* W_init  = (const float*)d_in[3];
    const float* b_init  = (const float*)d_in[4];
    const float* emb     = (const float*)d_in[5];
    const float* W_ih    = (const float*)d_in[6];
    const float* W_hh    = (const float*)d_in[7];
    const float* b_ih    = (const float*)d_in[8];
    const float* b_hh    = (const float*)d_in[9];
    const float* W_out   = (const float*)d_in[10];
    const float* b_out   = (const float*)d_in[11];
    float* out = (float*)d_out;

    // ---- workspace layout (~39.9 MB) ----
    float* h       = (float*)d_ws;                // 2 x 65536 f32 (ping-pong)
    float* esum    = h + 131072;                  // 2 x 5120 f32 (ping-pong)
    ushort* ub     = (ushort*)(esum + 10240);
    ushort* ghp    = ub;                          // 393216
    ushort* WhhB   = ghp + 393216;                // 786432
    ushort* WoutB  = WhhB + 786432;               // 2621440
    ushort* WcombT = WoutB + 2621440;             // 7864320
    ushort* hB     = WcombT + 7864320;            // 2 x 65536
    ushort* giP    = hB + 131072;                 // 40 x 196608 = 7864320
    // init-only buffers overlaid on giP (dead after k_wh0; giP zeroed by k_gh0)
    ushort* embB   = giP;                         // 1310720
    ushort* WihB   = embB + 1310720;              // 393216
    ushort* noiseB = WihB + 393216;               // 16384
    ushort* WinitB = noiseB + 16384;              // 65536

    k_prep<<<dim3(512), dim3(256), 0, stream>>>(
        W_ih, W_hh, W_out, noise, W_init, emb,
        WihB, WhhB, WoutB, noiseB, WinitB, embB);
    k_wh0<<<dim3(484), dim3(256), 0, stream>>>(
        WihB, embB, noiseB, WinitB, b_init, WcombT, h, hB);
    k_gh0<<<dim3(240), dim3(256), 0, stream>>>(hB, WhhB, ghp, giP);

    for (int t = 0; t < Tq; ++t) {
        float* h_old = h + (size_t)(t & 1) * 65536;
        float* h_new = h + (size_t)((t + 1) & 1) * 65536;
        ushort* hB_new = hB + (size_t)((t + 1) & 1) * 65536;
        float* esumPrev = esum + (size_t)((t + 1) & 1) * 5120;  // slice (t-1)&1
        float* esumCur  = esum + (size_t)(t & 1) * 5120;

        k_Q<<<dim3(192), dim3(256), 0, stream>>>(
            giP, ghp, b_ih, b_hh, h_old, esumPrev, h_new, hB_new, out, t);
        k_P<<<dim3(t + 1 < Tq ? 208 : 160), dim3(256), 0, stream>>>(
            hB_new, WoutB, WhhB, WcombT, b_out,
            gumbel + (size_t)t * Bq * Vq, temp,
            out, esumCur, giP, ghp, t);
    }
    k_tail<<<dim3(64), dim3(256), 0, stream>>>(
        out, esum + (size_t)((Tq - 1) & 1) * 5120);
}